// Round 11
// baseline (1664.854 us; speedup 1.0000x reference)
//
#include <hip/hip_runtime.h>
#include <hip/hip_bf16.h>

// ---------------------------------------------------------------------------
// DynamiSE: encoder GEMM -> 2x GCNConv (atomic scatter) -> fused dopri5 ODE.
// Round 11 = round-10 resubmit (round-10 bench was an infra flake; container
// died before source push). Set the VGPR budget via GEOMETRY, not attributes:
//   r5/r6/r8/r9: every launch-bounds / waves_per_eu knob left VGPR=128 and
//   ~1.8GB scratch. Model: LLVM derives the register budget from
//   LDS-achievable occupancy -- 64KB/block @512thr -> 2 blocks/CU -> 4
//   waves/SIMD -> 512/4 = 128 regs. Evidence: r4's fp32 kernel (98.8KB LDS
//   -> 1 block/CU) got VGPR=112, no scratch.
//   Fix: pad LDS to 96KB (yis doubled, only first 32KB used) -> 1 block/CU
//   -> 2 waves/SIMD -> budget 256 -> ~160 live regs fit, zero spill.
//   Numerics identical (absmax 3.9e-3).
// ---------------------------------------------------------------------------

typedef __attribute__((ext_vector_type(8))) short short8v;   // 8 bf16 = 4 VGPR
typedef __attribute__((ext_vector_type(4))) float f32x4;
typedef __attribute__((ext_vector_type(2))) unsigned uint2v;

__device__ __forceinline__ float fast_tanh(float x) {
    float e = __builtin_amdgcn_exp2f(x * 2.8853900817779268f);
    return 1.0f - 2.0f * __builtin_amdgcn_rcpf(e + 1.0f);
}

__device__ __forceinline__ unsigned bf16r(float x) {   // RTNE f32->bf16 bits
    unsigned u = __float_as_uint(x);
    return (u + 0x7fffu + ((u >> 16) & 1u)) >> 16;
}
__device__ __forceinline__ unsigned pack2(float lo, float hi) {
    return bf16r(lo) | (bf16r(hi) << 16);
}
__device__ __forceinline__ float unpk(unsigned u, int hi) {
    return __uint_as_float(hi ? (u & 0xffff0000u) : (u << 16));
}
#define KK(A, N, R) unpk(A[(N)*2 + ((R) >> 1)], (R) & 1)

// ---------------- degree / dinv ----------------

__global__ __launch_bounds__(256) void deg_init_kernel(float* degp, float* degn, int n) {
    int i = blockIdx.x * 256 + threadIdx.x;
    if (i < n) { degp[i] = 1.0f; degn[i] = 1.0f; }
}

__global__ __launch_bounds__(256) void deg_count_kernel(const int* __restrict__ pdst,
        const int* __restrict__ ndst, float* degp, float* degn, int nE) {
    int e = blockIdx.x * 256 + threadIdx.x;
    if (e < nE) {
        atomicAdd(&degp[pdst[e]], 1.0f);
        atomicAdd(&degn[ndst[e]], 1.0f);
    }
}

__global__ __launch_bounds__(256) void dinv_kernel(float* degp, float* degn, int n) {
    int i = blockIdx.x * 256 + threadIdx.x;
    if (i < n) { degp[i] = rsqrtf(degp[i]); degn[i] = rsqrtf(degn[i]); }
}

// ---------------- encoder: h = x @ W_enc + b_enc ----------------

__global__ __launch_bounds__(256) void encoder_kernel(const float* __restrict__ x,
        const float* __restrict__ W, const float* __restrict__ b,
        float* __restrict__ h, int n) {
    __shared__ __align__(16) float Ws[128 * 64];
    __shared__ __align__(16) float xs[4 * 128];
    int tid = threadIdx.x;
    for (int i = tid; i < 128 * 64; i += 256) Ws[i] = W[i];
    long row = (long)blockIdx.x * 4;
    for (int i = tid; i < 4 * 128; i += 256) {
        long rr = row + (i >> 7);
        xs[i] = (rr < n) ? x[rr * 128 + (i & 127)] : 0.0f;
    }
    __syncthreads();
    int r = tid >> 6, c = tid & 63;
    float acc = b[c];
    #pragma unroll 8
    for (int k = 0; k < 128; k += 4) {
        float4 xv = *(const float4*)&xs[r * 128 + k];
        acc += xv.x * Ws[(k+0)*64+c] + xv.y * Ws[(k+1)*64+c]
             + xv.z * Ws[(k+2)*64+c] + xv.w * Ws[(k+3)*64+c];
    }
    if (row + r < n) h[(row + r) * 64 + c] = acc;
}

// ---------------- hw' = dinv * (h @ W) for both graphs ----------------

__global__ __launch_bounds__(256) void hw_kernel(const float* __restrict__ h,
        const float* __restrict__ Wp, const float* __restrict__ Wn,
        const float* __restrict__ dinvp, const float* __restrict__ dinvn,
        float* __restrict__ hwp, float* __restrict__ hwn, int n) {
    __shared__ __align__(16) float Wps[64 * 64];
    __shared__ __align__(16) float Wns[64 * 64];
    __shared__ __align__(16) float hs[4 * 64];
    int tid = threadIdx.x;
    for (int i = tid; i < 64 * 64; i += 256) { Wps[i] = Wp[i]; Wns[i] = Wn[i]; }
    long row = (long)blockIdx.x * 4;
    {
        int i = tid;
        long rr = row + (i >> 6);
        hs[i] = (rr < n) ? h[rr * 64 + (i & 63)] : 0.0f;
    }
    __syncthreads();
    int r = tid >> 6, c = tid & 63;
    float ap = 0.0f, an = 0.0f;
    #pragma unroll 4
    for (int k = 0; k < 64; k += 4) {
        float4 hv = *(const float4*)&hs[r * 64 + k];
        ap += hv.x*Wps[(k+0)*64+c] + hv.y*Wps[(k+1)*64+c] + hv.z*Wps[(k+2)*64+c] + hv.w*Wps[(k+3)*64+c];
        an += hv.x*Wns[(k+0)*64+c] + hv.y*Wns[(k+1)*64+c] + hv.z*Wns[(k+2)*64+c] + hv.w*Wns[(k+3)*64+c];
    }
    if (row + r < n) {
        hwp[(row + r) * 64 + c] = ap * dinvp[row + r];
        hwn[(row + r) * 64 + c] = an * dinvn[row + r];
    }
}

// ---------------- y0 init / scatter / finalize ----------------

__global__ __launch_bounds__(256) void y0_init_kernel(const float* __restrict__ hwp,
        const float* __restrict__ hwn, float* __restrict__ y0, int n) {
    long idx = (long)blockIdx.x * 256 + threadIdx.x;
    if (idx >= (long)n * 128) return;
    long i = idx >> 7; int c = (int)(idx & 127);
    y0[idx] = (c < 64) ? hwp[i * 64 + c] : hwn[i * 64 + (c - 64)];
}

__global__ __launch_bounds__(256) void scatter_kernel(const int* __restrict__ src,
        const int* __restrict__ dst, const float* __restrict__ hw,
        float* __restrict__ y0, int colOff, int nE) {
    int wid  = blockIdx.x * 4 + (threadIdx.x >> 6);
    int lane = threadIdx.x & 63;
    if (wid >= nE) return;
    int s = src[wid], d = dst[wid];
    atomicAdd(&y0[(long)d * 128 + colOff + lane], hw[(long)s * 64 + lane]);
}

__global__ __launch_bounds__(256) void finalize_kernel(float* __restrict__ y0,
        const float* __restrict__ dinvp, const float* __restrict__ dinvn,
        const float* __restrict__ bp, const float* __restrict__ bn, int n) {
    long idx = (long)blockIdx.x * 256 + threadIdx.x;
    if (idx >= (long)n * 128) return;
    long i = idx >> 7; int c = (int)(idx & 127);
    if (c < 64) y0[idx] = dinvp[i] * y0[idx] + bp[c];
    else        y0[idx] = dinvn[i] * y0[idx] + bn[c - 64];
}

// ---------------- fused dopri5 ODE, bf16 MFMA ----------------
// Block: 512 threads = 8 waves; wave w owns rows [w*16, w*16+16) of a
// 128-row tile. Per MFMA (16x16x32, swapped operands):
//   acc[n][r] (lane) = out[row = w*16+(lane&15)][c = n*16 + (lane>>4)*4 + r]
//   A-frag: Wt[n*16 + (lane&15)][kk*32 + (lane>>4)*8 + j]   (ds_read_b128)
//   B-frag: yi[w*16 + (lane&15)][kk*32 + (lane>>4)*8 + j]   (ds_read_b128)
// All LDS rows are 256B, byte offsets XOR-swizzled with (row&7)<<4.
// Residual SQ_LDS_BANK_CONFLICT (~1e8 ticks) is the structural 2-way
// (lanes l15=s and s+8 share banks) -- free in time per m136.

template <typename F, typename C>
__device__ __forceinline__ void ode_stage_m(F yi_f, C consume, const unsigned bpk[16],
        char* yrow, const char* wtb, int l15, int q16, int q8, int swz) {
    #pragma unroll
    for (int n = 0; n < 8; ++n) {
        uint2v pk;
        pk.x = pack2(yi_f(n, 0), yi_f(n, 1));
        pk.y = pack2(yi_f(n, 2), yi_f(n, 3));
        *(uint2v*)(yrow + ((n * 32 + q8) ^ swz)) = pk;
    }
    // wave-local: our lanes' writes -> our lanes' reads; no barrier needed
    asm volatile("s_waitcnt lgkmcnt(0)" ::: "memory");
    short8v b0 = *(const short8v*)(yrow + ((  0 + q16) ^ swz));
    short8v b1 = *(const short8v*)(yrow + (( 64 + q16) ^ swz));
    short8v b2 = *(const short8v*)(yrow + ((128 + q16) ^ swz));
    short8v b3 = *(const short8v*)(yrow + ((192 + q16) ^ swz));
    #pragma unroll
    for (int n = 0; n < 8; ++n) {
        const char* ab = wtb + (n * 16 + l15) * 256;
        f32x4 a;
        a[0] = KK(bpk, n, 0); a[1] = KK(bpk, n, 1);
        a[2] = KK(bpk, n, 2); a[3] = KK(bpk, n, 3);
        a = __builtin_amdgcn_mfma_f32_16x16x32_bf16(*(const short8v*)(ab + ((  0 + q16) ^ swz)), b0, a, 0, 0, 0);
        a = __builtin_amdgcn_mfma_f32_16x16x32_bf16(*(const short8v*)(ab + (( 64 + q16) ^ swz)), b1, a, 0, 0, 0);
        a = __builtin_amdgcn_mfma_f32_16x16x32_bf16(*(const short8v*)(ab + ((128 + q16) ^ swz)), b2, a, 0, 0, 0);
        a = __builtin_amdgcn_mfma_f32_16x16x32_bf16(*(const short8v*)(ab + ((192 + q16) ^ swz)), b3, a, 0, 0, 0);
        consume(n, fast_tanh(a[0]), fast_tanh(a[1]), fast_tanh(a[2]), fast_tanh(a[3]));
    }
}

#define PACK_TO(KP) [&](int n, float t0, float t1, float t2, float t3) { \
        KP[n * 2]     = pack2(t0, t1);                                   \
        KP[n * 2 + 1] = pack2(t2, t3); }

__global__ __launch_bounds__(512)
__attribute__((amdgpu_waves_per_eu(2, 2)))
void ode_mfma_kernel(const float* __restrict__ y0,
        float* __restrict__ out, const float* __restrict__ W,
        const float* __restrict__ bb, const float* __restrict__ tt, int nrows) {
    __shared__ __align__(16) unsigned short Wt[16384];   // W^T bf16, swizzled, 32KB
    // 64KB declared, first 32KB used (128 rows x 256B). The padding is the
    // POINT: 96KB total LDS -> 1 block/CU -> 2 waves/SIMD -> 256-VGPR budget
    // (LLVM derives the register budget from LDS-achievable occupancy; every
    // attribute-based attempt at this left budget=128 and spilled).
    __shared__ __align__(16) unsigned short yis[32768];
    int tid  = threadIdx.x;
    int lane = tid & 63, w = tid >> 6;
    int l15 = lane & 15, q = lane >> 4;
    int swz = (lane & 7) << 4, q16 = q * 16, q8 = q * 8;

    // stage W^T (bf16, swizzled): Wt[c][d] = W[d][c]
    for (int i = tid; i < 16384; i += 512) {
        int d = i >> 7, c = i & 127;
        unsigned short hb = (unsigned short)bf16r(W[i]);
        *(unsigned short*)((char*)Wt + c * 256 + ((d * 2) ^ ((c & 7) << 4))) = hb;
    }

    float hstep = (tt[1] - tt[0]) * 0.03125f;

    // bias packed bf16 in D layout: c = n*16 + q*4 + r
    unsigned bpk[16];
    #pragma unroll
    for (int n = 0; n < 8; ++n) {
        f32x4 bv = *(const f32x4*)&bb[n * 16 + q * 4];
        bpk[n * 2]     = pack2(bv[0], bv[1]);
        bpk[n * 2 + 1] = pack2(bv[2], bv[3]);
    }

    long grow = (long)blockIdx.x * 128 + w * 16 + l15;
    bool ok = grow < nrows;

    f32x4 y[8];
    #pragma unroll
    for (int n = 0; n < 8; ++n) {
        if (ok) y[n] = *(const f32x4*)&y0[grow * 128 + n * 16 + q * 4];
        else    y[n] = (f32x4){0.0f, 0.0f, 0.0f, 0.0f};
    }

    __syncthreads();  // Wt ready (only barrier in the kernel)

    char* yrow = (char*)yis + (w * 16 + l15) * 256;
    const char* wtb = (const char*)Wt;

    unsigned kp1[16], kp2[16], kp3[16], kp4[16], kp5[16];

    #pragma unroll 1
    for (int step = 0; step < 32; ++step) {
        // stage 1: k1 = f(y)
        ode_stage_m([&](int n, int r) { return y[n][r]; },
                    PACK_TO(kp1), bpk, yrow, wtb, l15, q16, q8, swz);
        // stage 2
        ode_stage_m([&](int n, int r) { return y[n][r] + hstep * (0.2f * KK(kp1, n, r)); },
                    PACK_TO(kp2), bpk, yrow, wtb, l15, q16, q8, swz);
        // stage 3
        ode_stage_m([&](int n, int r) { return y[n][r] + hstep * (0.075f * KK(kp1, n, r)
                                                                + 0.225f * KK(kp2, n, r)); },
                    PACK_TO(kp3), bpk, yrow, wtb, l15, q16, q8, swz);
        // stage 4
        ode_stage_m([&](int n, int r) { return y[n][r] + hstep * (0.9777777777777777f  * KK(kp1, n, r)
                                                                - 3.7333333333333334f * KK(kp2, n, r)
                                                                + 3.5555555555555554f * KK(kp3, n, r)); },
                    PACK_TO(kp4), bpk, yrow, wtb, l15, q16, q8, swz);
        // stage 5
        ode_stage_m([&](int n, int r) { return y[n][r] + hstep * (2.9525986892242035f  * KK(kp1, n, r)
                                                                - 11.595793324188385f * KK(kp2, n, r)
                                                                + 9.822892851699436f  * KK(kp3, n, r)
                                                                - 0.2908093278463649f * KK(kp4, n, r)); },
                    PACK_TO(kp5), bpk, yrow, wtb, l15, q16, q8, swz);
        // stage 6: consume k6 directly into the 5th-order y-update
        ode_stage_m([&](int n, int r) { return y[n][r] + hstep * (2.8462752525252526f  * KK(kp1, n, r)
                                                                - 10.757575757575758f * KK(kp2, n, r)
                                                                + 8.906422717743473f  * KK(kp3, n, r)
                                                                + 0.2784090909090909f * KK(kp4, n, r)
                                                                - 0.2735313036020583f * KK(kp5, n, r)); },
                    [&](int n, float t0, float t1, float t2, float t3) {
                        float t[4] = {t0, t1, t2, t3};
                        #pragma unroll
                        for (int r = 0; r < 4; ++r)
                            y[n][r] += hstep * (0.09114583333333333f * KK(kp1, n, r)
                                              + 0.44923629829290207f * KK(kp3, n, r)
                                              + 0.6510416666666666f  * KK(kp4, n, r)
                                              - 0.322376179245283f   * KK(kp5, n, r)
                                              + 0.13095238095238096f * t[r]);
                    },
                    bpk, yrow, wtb, l15, q16, q8, swz);
    }

    if (ok) {
        #pragma unroll
        for (int n = 0; n < 8; ++n)
            *(f32x4*)&out[grow * 128 + n * 16 + q * 4] = y[n];
    }
}

// ---------------------------------------------------------------------------

extern "C" void kernel_launch(void* const* d_in, const int* in_sizes, int n_in,
                              void* d_out, int out_size, void* d_ws, size_t ws_size,
                              hipStream_t stream) {
    const float* x     = (const float*)d_in[0];
    const int*   pei   = (const int*)d_in[1];
    const int*   nei   = (const int*)d_in[2];
    const float* t     = (const float*)d_in[3];
    const float* W_enc = (const float*)d_in[4];
    const float* b_enc = (const float*)d_in[5];
    const float* W_pos = (const float*)d_in[6];
    const float* b_pos = (const float*)d_in[7];
    const float* W_neg = (const float*)d_in[8];
    const float* b_neg = (const float*)d_in[9];
    const float* W_ode = (const float*)d_in[10];
    const float* b_ode = (const float*)d_in[11];

    int n  = in_sizes[0] / 128;   // 50000 nodes
    int nE = in_sizes[1] / 2;     // 800000 edges

    // workspace layout (floats): h[n*64] | y0[n*128] | dinvp[n] | dinvn[n]
    float* ws    = (float*)d_ws;
    float* h     = ws;
    float* y0    = ws + (long)n * 64;
    float* dinvp = y0 + (long)n * 128;
    float* dinvn = dinvp + n;

    // d_out doubles as scratch for hw' (pos half then neg half), overwritten by ODE
    float* hwp = (float*)d_out;
    float* hwn = hwp + (long)n * 64;

    const int* psrc = pei;       const int* pdst = pei + nE;
    const int* nsrc = nei;       const int* ndst = nei + nE;

    int nbN  = (n + 255) / 256;
    int nbE  = (nE + 255) / 256;
    int nbR  = (n + 3) / 4;
    long tot = (long)n * 128;
    int nbT  = (int)((tot + 255) / 256);

    deg_init_kernel <<<nbN, 256, 0, stream>>>(dinvp, dinvn, n);
    deg_count_kernel<<<nbE, 256, 0, stream>>>(pdst, ndst, dinvp, dinvn, nE);
    dinv_kernel     <<<nbN, 256, 0, stream>>>(dinvp, dinvn, n);
    encoder_kernel  <<<nbR, 256, 0, stream>>>(x, W_enc, b_enc, h, n);
    hw_kernel       <<<nbR, 256, 0, stream>>>(h, W_pos, W_neg, dinvp, dinvn, hwp, hwn, n);
    y0_init_kernel  <<<nbT, 256, 0, stream>>>(hwp, hwn, y0, n);
    scatter_kernel  <<<(nE + 3) / 4, 256, 0, stream>>>(psrc, pdst, hwp, y0, 0,  nE);
    scatter_kernel  <<<(nE + 3) / 4, 256, 0, stream>>>(nsrc, ndst, hwn, y0, 64, nE);
    finalize_kernel <<<nbT, 256, 0, stream>>>(y0, dinvp, dinvn, b_pos, b_neg, n);
    ode_mfma_kernel <<<(n + 127) / 128, 512, 0, stream>>>(y0, (float*)d_out, W_ode, b_ode, t, n);
}

// Round 12
// 1624.582 us; speedup vs baseline: 1.0248x; 1.0248x over previous
//
#include <hip/hip_runtime.h>
#include <hip/hip_bf16.h>

// ---------------------------------------------------------------------------
// DynamiSE: encoder GEMM -> 2x GCNConv (atomic scatter) -> fused dopri5 ODE.
// Round 12: stop fighting the 128-VGPR cap -- fit under it.
//   r5-r11: 5 knob attempts (launch_bounds 2nd arg x3, waves_per_eu, LDS
//   padding) all left VGPR=128 + ~1.8GB scratch traffic. Whether the cause
//   is a hard 4-waves/EU allocator target or SROA failure on lambda-captured
//   arrays, the fix below beats both:
//   - wave-PAIR split: wave w -> rows of pair p=w>>1, cols n in {half*4..+3}
//     (half=w&1). Per-thread state: y 16 + kp 40 + bpk 8 = 64 persistent
//     regs (~100 with transients) < 128.
//   - stages are preprocessor macros (no lambdas, no address-taken arrays,
//     all indices literal after unroll).
//   - B-fragment needs partner's yi half -> 1 __syncthreads per stage with
//     double-buffered yi tiles (A/B). LDS = 32K Wt + 2x16K yi = 64KB,
//     64 rows/block, grid 782.
//   Numerics identical to r8 (absmax 3.9e-3).
// ---------------------------------------------------------------------------

typedef __attribute__((ext_vector_type(8))) short short8v;   // 8 bf16 = 4 VGPR
typedef __attribute__((ext_vector_type(4))) float f32x4;
typedef __attribute__((ext_vector_type(2))) unsigned uint2v;

__device__ __forceinline__ float fast_tanh(float x) {
    float e = __builtin_amdgcn_exp2f(x * 2.8853900817779268f);
    return 1.0f - 2.0f * __builtin_amdgcn_rcpf(e + 1.0f);
}

__device__ __forceinline__ unsigned bf16r(float x) {   // RTNE f32->bf16 bits
    unsigned u = __float_as_uint(x);
    return (u + 0x7fffu + ((u >> 16) & 1u)) >> 16;
}
__device__ __forceinline__ unsigned pack2(float lo, float hi) {
    return bf16r(lo) | (bf16r(hi) << 16);
}
__device__ __forceinline__ float unpk(unsigned u, int hi) {
    return __uint_as_float(hi ? (u & 0xffff0000u) : (u << 16));
}
#define KK(A, N, R) unpk(A[(N)*2 + ((R) >> 1)], (R) & 1)

// ---------------- degree / dinv ----------------

__global__ __launch_bounds__(256) void deg_init_kernel(float* degp, float* degn, int n) {
    int i = blockIdx.x * 256 + threadIdx.x;
    if (i < n) { degp[i] = 1.0f; degn[i] = 1.0f; }
}

__global__ __launch_bounds__(256) void deg_count_kernel(const int* __restrict__ pdst,
        const int* __restrict__ ndst, float* degp, float* degn, int nE) {
    int e = blockIdx.x * 256 + threadIdx.x;
    if (e < nE) {
        atomicAdd(&degp[pdst[e]], 1.0f);
        atomicAdd(&degn[ndst[e]], 1.0f);
    }
}

__global__ __launch_bounds__(256) void dinv_kernel(float* degp, float* degn, int n) {
    int i = blockIdx.x * 256 + threadIdx.x;
    if (i < n) { degp[i] = rsqrtf(degp[i]); degn[i] = rsqrtf(degn[i]); }
}

// ---------------- encoder: h = x @ W_enc + b_enc ----------------

__global__ __launch_bounds__(256) void encoder_kernel(const float* __restrict__ x,
        const float* __restrict__ W, const float* __restrict__ b,
        float* __restrict__ h, int n) {
    __shared__ __align__(16) float Ws[128 * 64];
    __shared__ __align__(16) float xs[4 * 128];
    int tid = threadIdx.x;
    for (int i = tid; i < 128 * 64; i += 256) Ws[i] = W[i];
    long row = (long)blockIdx.x * 4;
    for (int i = tid; i < 4 * 128; i += 256) {
        long rr = row + (i >> 7);
        xs[i] = (rr < n) ? x[rr * 128 + (i & 127)] : 0.0f;
    }
    __syncthreads();
    int r = tid >> 6, c = tid & 63;
    float acc = b[c];
    #pragma unroll 8
    for (int k = 0; k < 128; k += 4) {
        float4 xv = *(const float4*)&xs[r * 128 + k];
        acc += xv.x * Ws[(k+0)*64+c] + xv.y * Ws[(k+1)*64+c]
             + xv.z * Ws[(k+2)*64+c] + xv.w * Ws[(k+3)*64+c];
    }
    if (row + r < n) h[(row + r) * 64 + c] = acc;
}

// ---------------- hw' = dinv * (h @ W) for both graphs ----------------

__global__ __launch_bounds__(256) void hw_kernel(const float* __restrict__ h,
        const float* __restrict__ Wp, const float* __restrict__ Wn,
        const float* __restrict__ dinvp, const float* __restrict__ dinvn,
        float* __restrict__ hwp, float* __restrict__ hwn, int n) {
    __shared__ __align__(16) float Wps[64 * 64];
    __shared__ __align__(16) float Wns[64 * 64];
    __shared__ __align__(16) float hs[4 * 64];
    int tid = threadIdx.x;
    for (int i = tid; i < 64 * 64; i += 256) { Wps[i] = Wp[i]; Wns[i] = Wn[i]; }
    long row = (long)blockIdx.x * 4;
    {
        int i = tid;
        long rr = row + (i >> 6);
        hs[i] = (rr < n) ? h[rr * 64 + (i & 63)] : 0.0f;
    }
    __syncthreads();
    int r = tid >> 6, c = tid & 63;
    float ap = 0.0f, an = 0.0f;
    #pragma unroll 4
    for (int k = 0; k < 64; k += 4) {
        float4 hv = *(const float4*)&hs[r * 64 + k];
        ap += hv.x*Wps[(k+0)*64+c] + hv.y*Wps[(k+1)*64+c] + hv.z*Wps[(k+2)*64+c] + hv.w*Wps[(k+3)*64+c];
        an += hv.x*Wns[(k+0)*64+c] + hv.y*Wns[(k+1)*64+c] + hv.z*Wns[(k+2)*64+c] + hv.w*Wns[(k+3)*64+c];
    }
    if (row + r < n) {
        hwp[(row + r) * 64 + c] = ap * dinvp[row + r];
        hwn[(row + r) * 64 + c] = an * dinvn[row + r];
    }
}

// ---------------- y0 init / scatter / finalize ----------------

__global__ __launch_bounds__(256) void y0_init_kernel(const float* __restrict__ hwp,
        const float* __restrict__ hwn, float* __restrict__ y0, int n) {
    long idx = (long)blockIdx.x * 256 + threadIdx.x;
    if (idx >= (long)n * 128) return;
    long i = idx >> 7; int c = (int)(idx & 127);
    y0[idx] = (c < 64) ? hwp[i * 64 + c] : hwn[i * 64 + (c - 64)];
}

__global__ __launch_bounds__(256) void scatter_kernel(const int* __restrict__ src,
        const int* __restrict__ dst, const float* __restrict__ hw,
        float* __restrict__ y0, int colOff, int nE) {
    int wid  = blockIdx.x * 4 + (threadIdx.x >> 6);
    int lane = threadIdx.x & 63;
    if (wid >= nE) return;
    int s = src[wid], d = dst[wid];
    atomicAdd(&y0[(long)d * 128 + colOff + lane], hw[(long)s * 64 + lane]);
}

__global__ __launch_bounds__(256) void finalize_kernel(float* __restrict__ y0,
        const float* __restrict__ dinvp, const float* __restrict__ dinvn,
        const float* __restrict__ bp, const float* __restrict__ bn, int n) {
    long idx = (long)blockIdx.x * 256 + threadIdx.x;
    if (idx >= (long)n * 128) return;
    long i = idx >> 7; int c = (int)(idx & 127);
    if (c < 64) y0[idx] = dinvp[i] * y0[idx] + bp[c];
    else        y0[idx] = dinvn[i] * y0[idx] + bn[c - 64];
}

// ---------------- fused dopri5 ODE, bf16 MFMA, wave-pair split ----------------
// 512 threads = 8 waves = 4 pairs; pair p owns rows [p*16, p*16+16) of a
// 64-row tile; wave half=w&1 computes output cols n in {half*4 .. half*4+3}.
// Per MFMA (16x16x32, swapped operands, as verified in rounds 5-11):
//   acc[r] (lane) = out[row = p*16+(lane&15)][c = n*16 + (lane>>4)*4 + r]
//   A-frag: Wt[n*16 + (lane&15)][(lane>>4)*8 + j]   (ds_read_b128)
//   B-frag: yi[p*16 + (lane&15)][(lane>>4)*8 + j]   (ds_read_b128, FULL row
//           -> needs partner's half -> per-stage barrier, dbuf'd yi tiles)
// 256B rows, XOR-swizzled with (row&7)<<4 == (lane&7)<<4 per-lane const.

#define ODE_STAGE(BUF, YIM, CONSM) {                                                \
    char* yr_ = (BUF) + rowoff;                                                     \
    uint2v pk_;                                                                     \
    pk_.x = pack2(YIM(0,0), YIM(0,1)); pk_.y = pack2(YIM(0,2), YIM(0,3));           \
    *(uint2v*)(yr_ + (((half4+0)*32 + q8) ^ swz)) = pk_;                            \
    pk_.x = pack2(YIM(1,0), YIM(1,1)); pk_.y = pack2(YIM(1,2), YIM(1,3));           \
    *(uint2v*)(yr_ + (((half4+1)*32 + q8) ^ swz)) = pk_;                            \
    pk_.x = pack2(YIM(2,0), YIM(2,1)); pk_.y = pack2(YIM(2,2), YIM(2,3));           \
    *(uint2v*)(yr_ + (((half4+2)*32 + q8) ^ swz)) = pk_;                            \
    pk_.x = pack2(YIM(3,0), YIM(3,1)); pk_.y = pack2(YIM(3,2), YIM(3,3));           \
    *(uint2v*)(yr_ + (((half4+3)*32 + q8) ^ swz)) = pk_;                            \
    __syncthreads();                                                                \
    short8v b0 = *(const short8v*)(yr_ + ((  0 + q16) ^ swz));                      \
    short8v b1 = *(const short8v*)(yr_ + (( 64 + q16) ^ swz));                      \
    short8v b2 = *(const short8v*)(yr_ + ((128 + q16) ^ swz));                      \
    short8v b3 = *(const short8v*)(yr_ + ((192 + q16) ^ swz));                      \
    _Pragma("unroll")                                                               \
    for (int nn = 0; nn < 4; ++nn) {                                                \
        const char* ab = wtb + ((half4 + nn) * 16 + l15) * 256;                     \
        f32x4 a;                                                                    \
        a[0] = KK(bpk,nn,0); a[1] = KK(bpk,nn,1);                                   \
        a[2] = KK(bpk,nn,2); a[3] = KK(bpk,nn,3);                                   \
        a = __builtin_amdgcn_mfma_f32_16x16x32_bf16(*(const short8v*)(ab + ((  0+q16)^swz)), b0, a, 0,0,0); \
        a = __builtin_amdgcn_mfma_f32_16x16x32_bf16(*(const short8v*)(ab + (( 64+q16)^swz)), b1, a, 0,0,0); \
        a = __builtin_amdgcn_mfma_f32_16x16x32_bf16(*(const short8v*)(ab + ((128+q16)^swz)), b2, a, 0,0,0); \
        a = __builtin_amdgcn_mfma_f32_16x16x32_bf16(*(const short8v*)(ab + ((192+q16)^swz)), b3, a, 0,0,0); \
        CONSM(nn, fast_tanh(a[0]), fast_tanh(a[1]), fast_tanh(a[2]), fast_tanh(a[3])); \
    } }

#define YI1(nn, r) (y[nn][r])
#define YI2(nn, r) (y[nn][r] + hstep * (0.2f * KK(kp1,nn,r)))
#define YI3(nn, r) (y[nn][r] + hstep * (0.075f * KK(kp1,nn,r) + 0.225f * KK(kp2,nn,r)))
#define YI4(nn, r) (y[nn][r] + hstep * (0.9777777777777777f  * KK(kp1,nn,r) \
                                      - 3.7333333333333334f * KK(kp2,nn,r) \
                                      + 3.5555555555555554f * KK(kp3,nn,r)))
#define YI5(nn, r) (y[nn][r] + hstep * (2.9525986892242035f  * KK(kp1,nn,r) \
                                      - 11.595793324188385f * KK(kp2,nn,r) \
                                      + 9.822892851699436f  * KK(kp3,nn,r) \
                                      - 0.2908093278463649f * KK(kp4,nn,r)))
#define YI6(nn, r) (y[nn][r] + hstep * (2.8462752525252526f  * KK(kp1,nn,r) \
                                      - 10.757575757575758f * KK(kp2,nn,r) \
                                      + 8.906422717743473f  * KK(kp3,nn,r) \
                                      + 0.2784090909090909f * KK(kp4,nn,r) \
                                      - 0.2735313036020583f * KK(kp5,nn,r)))

#define CONS1(nn,t0,t1,t2,t3) { kp1[(nn)*2] = pack2(t0,t1); kp1[(nn)*2+1] = pack2(t2,t3); }
#define CONS2(nn,t0,t1,t2,t3) { kp2[(nn)*2] = pack2(t0,t1); kp2[(nn)*2+1] = pack2(t2,t3); }
#define CONS3(nn,t0,t1,t2,t3) { kp3[(nn)*2] = pack2(t0,t1); kp3[(nn)*2+1] = pack2(t2,t3); }
#define CONS4(nn,t0,t1,t2,t3) { kp4[(nn)*2] = pack2(t0,t1); kp4[(nn)*2+1] = pack2(t2,t3); }
#define CONS5(nn,t0,t1,t2,t3) { kp5[(nn)*2] = pack2(t0,t1); kp5[(nn)*2+1] = pack2(t2,t3); }
#define CONS6(nn,t0,t1,t2,t3) {                                             \
    y[nn][0] += hstep * (0.09114583333333333f * KK(kp1,nn,0)                \
                       + 0.44923629829290207f * KK(kp3,nn,0)                \
                       + 0.6510416666666666f  * KK(kp4,nn,0)                \
                       - 0.322376179245283f   * KK(kp5,nn,0)                \
                       + 0.13095238095238096f * (t0));                      \
    y[nn][1] += hstep * (0.09114583333333333f * KK(kp1,nn,1)                \
                       + 0.44923629829290207f * KK(kp3,nn,1)                \
                       + 0.6510416666666666f  * KK(kp4,nn,1)                \
                       - 0.322376179245283f   * KK(kp5,nn,1)                \
                       + 0.13095238095238096f * (t1));                      \
    y[nn][2] += hstep * (0.09114583333333333f * KK(kp1,nn,2)                \
                       + 0.44923629829290207f * KK(kp3,nn,2)                \
                       + 0.6510416666666666f  * KK(kp4,nn,2)                \
                       - 0.322376179245283f   * KK(kp5,nn,2)                \
                       + 0.13095238095238096f * (t2));                      \
    y[nn][3] += hstep * (0.09114583333333333f * KK(kp1,nn,3)                \
                       + 0.44923629829290207f * KK(kp3,nn,3)                \
                       + 0.6510416666666666f  * KK(kp4,nn,3)                \
                       - 0.322376179245283f   * KK(kp5,nn,3)                \
                       + 0.13095238095238096f * (t3)); }

__global__ __launch_bounds__(512) void ode_mfma_kernel(const float* __restrict__ y0,
        float* __restrict__ out, const float* __restrict__ W,
        const float* __restrict__ bb, const float* __restrict__ tt, int nrows) {
    __shared__ __align__(16) unsigned short Wt[16384];   // W^T bf16, swizzled, 32KB
    __shared__ __align__(16) unsigned short yisA[8192];  // 64 rows x 256B, 16KB
    __shared__ __align__(16) unsigned short yisB[8192];  // double buffer, 16KB
    int tid  = threadIdx.x;
    int lane = tid & 63, w = tid >> 6;
    int p = w >> 1, half4 = (w & 1) * 4;
    int l15 = lane & 15, q = lane >> 4;
    int swz = (lane & 7) << 4, q16 = q * 16, q8 = q * 8;
    int rowoff = (p * 16 + l15) * 256;

    // stage W^T (bf16, swizzled): Wt[c][d] = W[d][c]
    for (int i = tid; i < 16384; i += 512) {
        int d = i >> 7, c = i & 127;
        unsigned short hb = (unsigned short)bf16r(W[i]);
        *(unsigned short*)((char*)Wt + c * 256 + ((d * 2) ^ ((c & 7) << 4))) = hb;
    }

    float hstep = (tt[1] - tt[0]) * 0.03125f;

    // bias packed bf16 in D layout for my 4 cols: c = (half4+nn)*16 + q*4 + r
    unsigned bpk[8];
    #pragma unroll
    for (int nn = 0; nn < 4; ++nn) {
        f32x4 bv = *(const f32x4*)&bb[(half4 + nn) * 16 + q * 4];
        bpk[nn * 2]     = pack2(bv[0], bv[1]);
        bpk[nn * 2 + 1] = pack2(bv[2], bv[3]);
    }

    long grow = (long)blockIdx.x * 64 + p * 16 + l15;
    bool ok = grow < nrows;

    f32x4 y[4];
    #pragma unroll
    for (int nn = 0; nn < 4; ++nn) {
        if (ok) y[nn] = *(const f32x4*)&y0[grow * 128 + (half4 + nn) * 16 + q * 4];
        else    y[nn] = (f32x4){0.0f, 0.0f, 0.0f, 0.0f};
    }

    char* bufA = (char*)yisA;
    char* bufB = (char*)yisB;
    const char* wtb = (const char*)Wt;

    unsigned kp1[8], kp2[8], kp3[8], kp4[8], kp5[8];

    #pragma unroll 1
    for (int step = 0; step < 32; ++step) {
        ODE_STAGE(bufA, YI1, CONS1);   // k1 = f(y)
        ODE_STAGE(bufB, YI2, CONS2);
        ODE_STAGE(bufA, YI3, CONS3);
        ODE_STAGE(bufB, YI4, CONS4);
        ODE_STAGE(bufA, YI5, CONS5);
        ODE_STAGE(bufB, YI6, CONS6);   // k6 folded into 5th-order y-update
    }

    if (ok) {
        #pragma unroll
        for (int nn = 0; nn < 4; ++nn)
            *(f32x4*)&out[grow * 128 + (half4 + nn) * 16 + q * 4] = y[nn];
    }
}

// ---------------------------------------------------------------------------

extern "C" void kernel_launch(void* const* d_in, const int* in_sizes, int n_in,
                              void* d_out, int out_size, void* d_ws, size_t ws_size,
                              hipStream_t stream) {
    const float* x     = (const float*)d_in[0];
    const int*   pei   = (const int*)d_in[1];
    const int*   nei   = (const int*)d_in[2];
    const float* t     = (const float*)d_in[3];
    const float* W_enc = (const float*)d_in[4];
    const float* b_enc = (const float*)d_in[5];
    const float* W_pos = (const float*)d_in[6];
    const float* b_pos = (const float*)d_in[7];
    const float* W_neg = (const float*)d_in[8];
    const float* b_neg = (const float*)d_in[9];
    const float* W_ode = (const float*)d_in[10];
    const float* b_ode = (const float*)d_in[11];

    int n  = in_sizes[0] / 128;   // 50000 nodes
    int nE = in_sizes[1] / 2;     // 800000 edges

    // workspace layout (floats): h[n*64] | y0[n*128] | dinvp[n] | dinvn[n]
    float* ws    = (float*)d_ws;
    float* h     = ws;
    float* y0    = ws + (long)n * 64;
    float* dinvp = y0 + (long)n * 128;
    float* dinvn = dinvp + n;

    // d_out doubles as scratch for hw' (pos half then neg half), overwritten by ODE
    float* hwp = (float*)d_out;
    float* hwn = hwp + (long)n * 64;

    const int* psrc = pei;       const int* pdst = pei + nE;
    const int* nsrc = nei;       const int* ndst = nei + nE;

    int nbN  = (n + 255) / 256;
    int nbE  = (nE + 255) / 256;
    int nbR  = (n + 3) / 4;
    long tot = (long)n * 128;
    int nbT  = (int)((tot + 255) / 256);

    deg_init_kernel <<<nbN, 256, 0, stream>>>(dinvp, dinvn, n);
    deg_count_kernel<<<nbE, 256, 0, stream>>>(pdst, ndst, dinvp, dinvn, nE);
    dinv_kernel     <<<nbN, 256, 0, stream>>>(dinvp, dinvn, n);
    encoder_kernel  <<<nbR, 256, 0, stream>>>(x, W_enc, b_enc, h, n);
    hw_kernel       <<<nbR, 256, 0, stream>>>(h, W_pos, W_neg, dinvp, dinvn, hwp, hwn, n);
    y0_init_kernel  <<<nbT, 256, 0, stream>>>(hwp, hwn, y0, n);
    scatter_kernel  <<<(nE + 3) / 4, 256, 0, stream>>>(psrc, pdst, hwp, y0, 0,  nE);
    scatter_kernel  <<<(nE + 3) / 4, 256, 0, stream>>>(nsrc, ndst, hwn, y0, 64, nE);
    finalize_kernel <<<nbT, 256, 0, stream>>>(y0, dinvp, dinvn, b_pos, b_neg, n);
    ode_mfma_kernel <<<(n + 63) / 64, 512, 0, stream>>>(y0, (float*)d_out, W_ode, b_ode, t, n);
}

// Round 13
// 1350.776 us; speedup vs baseline: 1.2325x; 1.2027x over previous
//
#include <hip/hip_runtime.h>
#include <hip/hip_bf16.h>

// ---------------------------------------------------------------------------
// DynamiSE: encoder GEMM -> 2x GCNConv (atomic scatter) -> fused dopri5 ODE.
// Round 13: attack serialization, not spill (r12 killed spill: 1219->1167 only;
// both pipes <50% -> barrier-chain bound).
//   - PAIR-BLOCKS: block = 128 threads = one wave pair owning 16 rows.
//     Barrier radius 8->2 waves; LDS 40KB -> 4 independent blocks/CU.
//   - v_cvt_pk_bf16_f32 (1 op / 2 values, HW RTNE) replaces 9-op pack2 at
//     all 16 uses/stage; bias kept unpacked f32x4 (kills 16 unpk/stage).
//   Numerics equivalent (RTNE == RTNE); absmax expected ~3.9e-3.
// ---------------------------------------------------------------------------

typedef __attribute__((ext_vector_type(8))) short short8v;   // 8 bf16 = 4 VGPR
typedef __attribute__((ext_vector_type(4))) float f32x4;
typedef __attribute__((ext_vector_type(2))) unsigned uint2v;

__device__ __forceinline__ float fast_tanh(float x) {
    float e = __builtin_amdgcn_exp2f(x * 2.8853900817779268f);
    return 1.0f - 2.0f * __builtin_amdgcn_rcpf(e + 1.0f);
}

__device__ __forceinline__ unsigned bf16r(float x) {   // RTNE f32->bf16 bits (host-side path for Wt staging)
    unsigned u = __float_as_uint(x);
    return (u + 0x7fffu + ((u >> 16) & 1u)) >> 16;
}
__device__ __forceinline__ unsigned cvt_pk(float lo, float hi) {  // 1 VALU op
    unsigned r;
    asm("v_cvt_pk_bf16_f32 %0, %1, %2" : "=v"(r) : "v"(lo), "v"(hi));
    return r;
}
__device__ __forceinline__ float unpk(unsigned u, int hi) {
    return __uint_as_float(hi ? (u & 0xffff0000u) : (u << 16));
}
#define KK(A, N, R) unpk(A[(N)*2 + ((R) >> 1)], (R) & 1)

// ---------------- degree / dinv ----------------

__global__ __launch_bounds__(256) void deg_init_kernel(float* degp, float* degn, int n) {
    int i = blockIdx.x * 256 + threadIdx.x;
    if (i < n) { degp[i] = 1.0f; degn[i] = 1.0f; }
}

__global__ __launch_bounds__(256) void deg_count_kernel(const int* __restrict__ pdst,
        const int* __restrict__ ndst, float* degp, float* degn, int nE) {
    int e = blockIdx.x * 256 + threadIdx.x;
    if (e < nE) {
        atomicAdd(&degp[pdst[e]], 1.0f);
        atomicAdd(&degn[ndst[e]], 1.0f);
    }
}

__global__ __launch_bounds__(256) void dinv_kernel(float* degp, float* degn, int n) {
    int i = blockIdx.x * 256 + threadIdx.x;
    if (i < n) { degp[i] = rsqrtf(degp[i]); degn[i] = rsqrtf(degn[i]); }
}

// ---------------- encoder: h = x @ W_enc + b_enc ----------------

__global__ __launch_bounds__(256) void encoder_kernel(const float* __restrict__ x,
        const float* __restrict__ W, const float* __restrict__ b,
        float* __restrict__ h, int n) {
    __shared__ __align__(16) float Ws[128 * 64];
    __shared__ __align__(16) float xs[4 * 128];
    int tid = threadIdx.x;
    for (int i = tid; i < 128 * 64; i += 256) Ws[i] = W[i];
    long row = (long)blockIdx.x * 4;
    for (int i = tid; i < 4 * 128; i += 256) {
        long rr = row + (i >> 7);
        xs[i] = (rr < n) ? x[rr * 128 + (i & 127)] : 0.0f;
    }
    __syncthreads();
    int r = tid >> 6, c = tid & 63;
    float acc = b[c];
    #pragma unroll 8
    for (int k = 0; k < 128; k += 4) {
        float4 xv = *(const float4*)&xs[r * 128 + k];
        acc += xv.x * Ws[(k+0)*64+c] + xv.y * Ws[(k+1)*64+c]
             + xv.z * Ws[(k+2)*64+c] + xv.w * Ws[(k+3)*64+c];
    }
    if (row + r < n) h[(row + r) * 64 + c] = acc;
}

// ---------------- hw' = dinv * (h @ W) for both graphs ----------------

__global__ __launch_bounds__(256) void hw_kernel(const float* __restrict__ h,
        const float* __restrict__ Wp, const float* __restrict__ Wn,
        const float* __restrict__ dinvp, const float* __restrict__ dinvn,
        float* __restrict__ hwp, float* __restrict__ hwn, int n) {
    __shared__ __align__(16) float Wps[64 * 64];
    __shared__ __align__(16) float Wns[64 * 64];
    __shared__ __align__(16) float hs[4 * 64];
    int tid = threadIdx.x;
    for (int i = tid; i < 64 * 64; i += 256) { Wps[i] = Wp[i]; Wns[i] = Wn[i]; }
    long row = (long)blockIdx.x * 4;
    {
        int i = tid;
        long rr = row + (i >> 6);
        hs[i] = (rr < n) ? h[rr * 64 + (i & 63)] : 0.0f;
    }
    __syncthreads();
    int r = tid >> 6, c = tid & 63;
    float ap = 0.0f, an = 0.0f;
    #pragma unroll 4
    for (int k = 0; k < 64; k += 4) {
        float4 hv = *(const float4*)&hs[r * 64 + k];
        ap += hv.x*Wps[(k+0)*64+c] + hv.y*Wps[(k+1)*64+c] + hv.z*Wps[(k+2)*64+c] + hv.w*Wps[(k+3)*64+c];
        an += hv.x*Wns[(k+0)*64+c] + hv.y*Wns[(k+1)*64+c] + hv.z*Wns[(k+2)*64+c] + hv.w*Wns[(k+3)*64+c];
    }
    if (row + r < n) {
        hwp[(row + r) * 64 + c] = ap * dinvp[row + r];
        hwn[(row + r) * 64 + c] = an * dinvn[row + r];
    }
}

// ---------------- y0 init / scatter / finalize ----------------

__global__ __launch_bounds__(256) void y0_init_kernel(const float* __restrict__ hwp,
        const float* __restrict__ hwn, float* __restrict__ y0, int n) {
    long idx = (long)blockIdx.x * 256 + threadIdx.x;
    if (idx >= (long)n * 128) return;
    long i = idx >> 7; int c = (int)(idx & 127);
    y0[idx] = (c < 64) ? hwp[i * 64 + c] : hwn[i * 64 + (c - 64)];
}

__global__ __launch_bounds__(256) void scatter_kernel(const int* __restrict__ src,
        const int* __restrict__ dst, const float* __restrict__ hw,
        float* __restrict__ y0, int colOff, int nE) {
    int wid  = blockIdx.x * 4 + (threadIdx.x >> 6);
    int lane = threadIdx.x & 63;
    if (wid >= nE) return;
    int s = src[wid], d = dst[wid];
    atomicAdd(&y0[(long)d * 128 + colOff + lane], hw[(long)s * 64 + lane]);
}

__global__ __launch_bounds__(256) void finalize_kernel(float* __restrict__ y0,
        const float* __restrict__ dinvp, const float* __restrict__ dinvn,
        const float* __restrict__ bp, const float* __restrict__ bn, int n) {
    long idx = (long)blockIdx.x * 256 + threadIdx.x;
    if (idx >= (long)n * 128) return;
    long i = idx >> 7; int c = (int)(idx & 127);
    if (c < 64) y0[idx] = dinvp[i] * y0[idx] + bp[c];
    else        y0[idx] = dinvn[i] * y0[idx] + bn[c - 64];
}

// ---------------- fused dopri5 ODE, bf16 MFMA, pair-block ----------------
// Block: 128 threads = 2 waves = ONE pair owning 16 rows. Wave w computes
// output cols n in {w*4 .. w*4+3}. Per MFMA (16x16x32, swapped operands):
//   acc[r] (lane) = out[row = lane&15][c = n*16 + (lane>>4)*4 + r]
//   A-frag: Wt[n*16 + (lane&15)][(lane>>4)*8 + j]   (ds_read_b128)
//   B-frag: yi[lane&15][(lane>>4)*8 + j]            (ds_read_b128, full row
//           -> needs partner wave's half -> per-stage barrier, dbuf'd yi)
// 256B rows, XOR-swizzled with (l15&7)<<4; bank-optimal (8-clock b128 min).

#define ODE_STAGE(BUF, YIM, CONSM) {                                                \
    char* yr_ = (BUF) + rowoff;                                                     \
    uint2v pk_;                                                                     \
    pk_.x = cvt_pk(YIM(0,0), YIM(0,1)); pk_.y = cvt_pk(YIM(0,2), YIM(0,3));         \
    *(uint2v*)(yr_ + (((half4+0)*32 + q8) ^ swz)) = pk_;                            \
    pk_.x = cvt_pk(YIM(1,0), YIM(1,1)); pk_.y = cvt_pk(YIM(1,2), YIM(1,3));         \
    *(uint2v*)(yr_ + (((half4+1)*32 + q8) ^ swz)) = pk_;                            \
    pk_.x = cvt_pk(YIM(2,0), YIM(2,1)); pk_.y = cvt_pk(YIM(2,2), YIM(2,3));         \
    *(uint2v*)(yr_ + (((half4+2)*32 + q8) ^ swz)) = pk_;                            \
    pk_.x = cvt_pk(YIM(3,0), YIM(3,1)); pk_.y = cvt_pk(YIM(3,2), YIM(3,3));         \
    *(uint2v*)(yr_ + (((half4+3)*32 + q8) ^ swz)) = pk_;                            \
    __syncthreads();                                                                \
    short8v b0 = *(const short8v*)(yr_ + ((  0 + q16) ^ swz));                      \
    short8v b1 = *(const short8v*)(yr_ + (( 64 + q16) ^ swz));                      \
    short8v b2 = *(const short8v*)(yr_ + ((128 + q16) ^ swz));                      \
    short8v b3 = *(const short8v*)(yr_ + ((192 + q16) ^ swz));                      \
    _Pragma("unroll")                                                               \
    for (int nn = 0; nn < 4; ++nn) {                                                \
        const char* ab = wtb + ((half4 + nn) * 16 + l15) * 256;                     \
        f32x4 a = bias_f[nn];                                                       \
        a = __builtin_amdgcn_mfma_f32_16x16x32_bf16(*(const short8v*)(ab + ((  0+q16)^swz)), b0, a, 0,0,0); \
        a = __builtin_amdgcn_mfma_f32_16x16x32_bf16(*(const short8v*)(ab + (( 64+q16)^swz)), b1, a, 0,0,0); \
        a = __builtin_amdgcn_mfma_f32_16x16x32_bf16(*(const short8v*)(ab + ((128+q16)^swz)), b2, a, 0,0,0); \
        a = __builtin_amdgcn_mfma_f32_16x16x32_bf16(*(const short8v*)(ab + ((192+q16)^swz)), b3, a, 0,0,0); \
        CONSM(nn, fast_tanh(a[0]), fast_tanh(a[1]), fast_tanh(a[2]), fast_tanh(a[3])); \
    } }

#define YI1(nn, r) (y[nn][r])
#define YI2(nn, r) (y[nn][r] + hstep * (0.2f * KK(kp1,nn,r)))
#define YI3(nn, r) (y[nn][r] + hstep * (0.075f * KK(kp1,nn,r) + 0.225f * KK(kp2,nn,r)))
#define YI4(nn, r) (y[nn][r] + hstep * (0.9777777777777777f  * KK(kp1,nn,r) \
                                      - 3.7333333333333334f * KK(kp2,nn,r) \
                                      + 3.5555555555555554f * KK(kp3,nn,r)))
#define YI5(nn, r) (y[nn][r] + hstep * (2.9525986892242035f  * KK(kp1,nn,r) \
                                      - 11.595793324188385f * KK(kp2,nn,r) \
                                      + 9.822892851699436f  * KK(kp3,nn,r) \
                                      - 0.2908093278463649f * KK(kp4,nn,r)))
#define YI6(nn, r) (y[nn][r] + hstep * (2.8462752525252526f  * KK(kp1,nn,r) \
                                      - 10.757575757575758f * KK(kp2,nn,r) \
                                      + 8.906422717743473f  * KK(kp3,nn,r) \
                                      + 0.2784090909090909f * KK(kp4,nn,r) \
                                      - 0.2735313036020583f * KK(kp5,nn,r)))

#define CONS1(nn,t0,t1,t2,t3) { kp1[(nn)*2] = cvt_pk(t0,t1); kp1[(nn)*2+1] = cvt_pk(t2,t3); }
#define CONS2(nn,t0,t1,t2,t3) { kp2[(nn)*2] = cvt_pk(t0,t1); kp2[(nn)*2+1] = cvt_pk(t2,t3); }
#define CONS3(nn,t0,t1,t2,t3) { kp3[(nn)*2] = cvt_pk(t0,t1); kp3[(nn)*2+1] = cvt_pk(t2,t3); }
#define CONS4(nn,t0,t1,t2,t3) { kp4[(nn)*2] = cvt_pk(t0,t1); kp4[(nn)*2+1] = cvt_pk(t2,t3); }
#define CONS5(nn,t0,t1,t2,t3) { kp5[(nn)*2] = cvt_pk(t0,t1); kp5[(nn)*2+1] = cvt_pk(t2,t3); }
#define CONS6(nn,t0,t1,t2,t3) {                                             \
    y[nn][0] += hstep * (0.09114583333333333f * KK(kp1,nn,0)                \
                       + 0.44923629829290207f * KK(kp3,nn,0)                \
                       + 0.6510416666666666f  * KK(kp4,nn,0)                \
                       - 0.322376179245283f   * KK(kp5,nn,0)                \
                       + 0.13095238095238096f * (t0));                      \
    y[nn][1] += hstep * (0.09114583333333333f * KK(kp1,nn,1)                \
                       + 0.44923629829290207f * KK(kp3,nn,1)                \
                       + 0.6510416666666666f  * KK(kp4,nn,1)                \
                       - 0.322376179245283f   * KK(kp5,nn,1)                \
                       + 0.13095238095238096f * (t1));                      \
    y[nn][2] += hstep * (0.09114583333333333f * KK(kp1,nn,2)                \
                       + 0.44923629829290207f * KK(kp3,nn,2)                \
                       + 0.6510416666666666f  * KK(kp4,nn,2)                \
                       - 0.322376179245283f   * KK(kp5,nn,2)                \
                       + 0.13095238095238096f * (t2));                      \
    y[nn][3] += hstep * (0.09114583333333333f * KK(kp1,nn,3)                \
                       + 0.44923629829290207f * KK(kp3,nn,3)                \
                       + 0.6510416666666666f  * KK(kp4,nn,3)                \
                       - 0.322376179245283f   * KK(kp5,nn,3)                \
                       + 0.13095238095238096f * (t3)); }

__global__ __launch_bounds__(128) void ode_mfma_kernel(const float* __restrict__ y0,
        float* __restrict__ out, const float* __restrict__ W,
        const float* __restrict__ bb, const float* __restrict__ tt, int nrows) {
    __shared__ __align__(16) unsigned short Wt[16384];   // W^T bf16, swizzled, 32KB
    __shared__ __align__(16) unsigned short yisA[2048];  // 16 rows x 256B, 4KB
    __shared__ __align__(16) unsigned short yisB[2048];  // double buffer, 4KB
    int tid  = threadIdx.x;
    int lane = tid & 63, w = tid >> 6;       // w in {0,1}: which col-half
    int half4 = w * 4;
    int l15 = lane & 15, q = lane >> 4;
    int swz = (lane & 7) << 4, q16 = q * 16, q8 = q * 8;
    int rowoff = l15 * 256;

    // stage W^T (bf16, swizzled): Wt[c][d] = W[d][c]
    for (int i = tid; i < 16384; i += 128) {
        int d = i >> 7, c = i & 127;
        unsigned short hb = (unsigned short)bf16r(W[i]);
        *(unsigned short*)((char*)Wt + c * 256 + ((d * 2) ^ ((c & 7) << 4))) = hb;
    }

    float hstep = (tt[1] - tt[0]) * 0.03125f;

    // bias (unpacked f32) in D layout for my 4 cols: c = (half4+nn)*16 + q*4 + r
    f32x4 bias_f[4];
    #pragma unroll
    for (int nn = 0; nn < 4; ++nn)
        bias_f[nn] = *(const f32x4*)&bb[(half4 + nn) * 16 + q * 4];

    long grow = (long)blockIdx.x * 16 + l15;
    bool ok = grow < nrows;

    f32x4 y[4];
    #pragma unroll
    for (int nn = 0; nn < 4; ++nn) {
        if (ok) y[nn] = *(const f32x4*)&y0[grow * 128 + (half4 + nn) * 16 + q * 4];
        else    y[nn] = (f32x4){0.0f, 0.0f, 0.0f, 0.0f};
    }

    char* bufA = (char*)yisA;
    char* bufB = (char*)yisB;
    const char* wtb = (const char*)Wt;

    unsigned kp1[8], kp2[8], kp3[8], kp4[8], kp5[8];

    __syncthreads();  // Wt ready

    #pragma unroll 1
    for (int step = 0; step < 32; ++step) {
        ODE_STAGE(bufA, YI1, CONS1);   // k1 = f(y)
        ODE_STAGE(bufB, YI2, CONS2);
        ODE_STAGE(bufA, YI3, CONS3);
        ODE_STAGE(bufB, YI4, CONS4);
        ODE_STAGE(bufA, YI5, CONS5);
        ODE_STAGE(bufB, YI6, CONS6);   // k6 folded into 5th-order y-update
    }

    if (ok) {
        #pragma unroll
        for (int nn = 0; nn < 4; ++nn)
            *(f32x4*)&out[grow * 128 + (half4 + nn) * 16 + q * 4] = y[nn];
    }
}

// ---------------------------------------------------------------------------

extern "C" void kernel_launch(void* const* d_in, const int* in_sizes, int n_in,
                              void* d_out, int out_size, void* d_ws, size_t ws_size,
                              hipStream_t stream) {
    const float* x     = (const float*)d_in[0];
    const int*   pei   = (const int*)d_in[1];
    const int*   nei   = (const int*)d_in[2];
    const float* t     = (const float*)d_in[3];
    const float* W_enc = (const float*)d_in[4];
    const float* b_enc = (const float*)d_in[5];
    const float* W_pos = (const float*)d_in[6];
    const float* b_pos = (const float*)d_in[7];
    const float* W_neg = (const float*)d_in[8];
    const float* b_neg = (const float*)d_in[9];
    const float* W_ode = (const float*)d_in[10];
    const float* b_ode = (const float*)d_in[11];

    int n  = in_sizes[0] / 128;   // 50000 nodes
    int nE = in_sizes[1] / 2;     // 800000 edges

    // workspace layout (floats): h[n*64] | y0[n*128] | dinvp[n] | dinvn[n]
    float* ws    = (float*)d_ws;
    float* h     = ws;
    float* y0    = ws + (long)n * 64;
    float* dinvp = y0 + (long)n * 128;
    float* dinvn = dinvp + n;

    // d_out doubles as scratch for hw' (pos half then neg half), overwritten by ODE
    float* hwp = (float*)d_out;
    float* hwn = hwp + (long)n * 64;

    const int* psrc = pei;       const int* pdst = pei + nE;
    const int* nsrc = nei;       const int* ndst = nei + nE;

    int nbN  = (n + 255) / 256;
    int nbE  = (nE + 255) / 256;
    int nbR  = (n + 3) / 4;
    long tot = (long)n * 128;
    int nbT  = (int)((tot + 255) / 256);

    deg_init_kernel <<<nbN, 256, 0, stream>>>(dinvp, dinvn, n);
    deg_count_kernel<<<nbE, 256, 0, stream>>>(pdst, ndst, dinvp, dinvn, nE);
    dinv_kernel     <<<nbN, 256, 0, stream>>>(dinvp, dinvn, n);
    encoder_kernel  <<<nbR, 256, 0, stream>>>(x, W_enc, b_enc, h, n);
    hw_kernel       <<<nbR, 256, 0, stream>>>(h, W_pos, W_neg, dinvp, dinvn, hwp, hwn, n);
    y0_init_kernel  <<<nbT, 256, 0, stream>>>(hwp, hwn, y0, n);
    scatter_kernel  <<<(nE + 3) / 4, 256, 0, stream>>>(psrc, pdst, hwp, y0, 0,  nE);
    scatter_kernel  <<<(nE + 3) / 4, 256, 0, stream>>>(nsrc, ndst, hwn, y0, 64, nE);
    finalize_kernel <<<nbT, 256, 0, stream>>>(y0, dinvp, dinvn, b_pos, b_neg, n);
    ode_mfma_kernel <<<(n + 15) / 16, 128, 0, stream>>>(y0, (float*)d_out, W_ode, b_ode, t, n);
}

// Round 14
// 1191.414 us; speedup vs baseline: 1.3974x; 1.1338x over previous
//
#include <hip/hip_runtime.h>
#include <hip/hip_bf16.h>

// ---------------------------------------------------------------------------
// DynamiSE: encoder GEMM -> 2x GCNConv (atomic scatter) -> fused dopri5 ODE.
// Round 14: A-fragment register cache + quad-split + LDS aliasing.
//   r13 (pair-block, cvt_pk): 903us, VALU 64 / MFMA 15 / occ 19.6 -- stage
//   time ~= LDS + VALU SUM (not max): the 16 A-reads (of constant W!) sit in
//   every stage's critical path. This round:
//   - block = 256 thr = 4 waves per 16-row group; wave w owns col-groups
//     {2w, 2w+1} -> A-frags = 8 short8v in REGISTERS (loaded once).
//     LDS reads/thread/stage: 20 -> 4 (B only).
//   - Wt LDS (32KB) is prologue-only -> yi double-buffers ALIAS into it.
//     LDS = exactly 32KB -> 5 blocks/CU, 20 waves/CU (2.5x r13's supply).
//   Numerics identical (absmax 3.9e-3).
// ---------------------------------------------------------------------------

typedef __attribute__((ext_vector_type(8))) short short8v;   // 8 bf16 = 4 VGPR
typedef __attribute__((ext_vector_type(4))) float f32x4;
typedef __attribute__((ext_vector_type(2))) unsigned uint2v;

__device__ __forceinline__ float fast_tanh(float x) {
    float e = __builtin_amdgcn_exp2f(x * 2.8853900817779268f);
    return 1.0f - 2.0f * __builtin_amdgcn_rcpf(e + 1.0f);
}

__device__ __forceinline__ unsigned bf16r(float x) {   // RTNE f32->bf16 bits
    unsigned u = __float_as_uint(x);
    return (u + 0x7fffu + ((u >> 16) & 1u)) >> 16;
}
__device__ __forceinline__ unsigned cvt_pk(float lo, float hi) {  // 1 VALU op
    unsigned r;
    asm("v_cvt_pk_bf16_f32 %0, %1, %2" : "=v"(r) : "v"(lo), "v"(hi));
    return r;
}
__device__ __forceinline__ float unpk(unsigned u, int hi) {
    return __uint_as_float(hi ? (u & 0xffff0000u) : (u << 16));
}
#define KK(A, N, R) unpk(A[(N)*2 + ((R) >> 1)], (R) & 1)

// ---------------- degree / dinv ----------------

__global__ __launch_bounds__(256) void deg_init_kernel(float* degp, float* degn, int n) {
    int i = blockIdx.x * 256 + threadIdx.x;
    if (i < n) { degp[i] = 1.0f; degn[i] = 1.0f; }
}

__global__ __launch_bounds__(256) void deg_count_kernel(const int* __restrict__ pdst,
        const int* __restrict__ ndst, float* degp, float* degn, int nE) {
    int e = blockIdx.x * 256 + threadIdx.x;
    if (e < nE) {
        atomicAdd(&degp[pdst[e]], 1.0f);
        atomicAdd(&degn[ndst[e]], 1.0f);
    }
}

__global__ __launch_bounds__(256) void dinv_kernel(float* degp, float* degn, int n) {
    int i = blockIdx.x * 256 + threadIdx.x;
    if (i < n) { degp[i] = rsqrtf(degp[i]); degn[i] = rsqrtf(degn[i]); }
}

// ---------------- encoder: h = x @ W_enc + b_enc ----------------

__global__ __launch_bounds__(256) void encoder_kernel(const float* __restrict__ x,
        const float* __restrict__ W, const float* __restrict__ b,
        float* __restrict__ h, int n) {
    __shared__ __align__(16) float Ws[128 * 64];
    __shared__ __align__(16) float xs[4 * 128];
    int tid = threadIdx.x;
    for (int i = tid; i < 128 * 64; i += 256) Ws[i] = W[i];
    long row = (long)blockIdx.x * 4;
    for (int i = tid; i < 4 * 128; i += 256) {
        long rr = row + (i >> 7);
        xs[i] = (rr < n) ? x[rr * 128 + (i & 127)] : 0.0f;
    }
    __syncthreads();
    int r = tid >> 6, c = tid & 63;
    float acc = b[c];
    #pragma unroll 8
    for (int k = 0; k < 128; k += 4) {
        float4 xv = *(const float4*)&xs[r * 128 + k];
        acc += xv.x * Ws[(k+0)*64+c] + xv.y * Ws[(k+1)*64+c]
             + xv.z * Ws[(k+2)*64+c] + xv.w * Ws[(k+3)*64+c];
    }
    if (row + r < n) h[(row + r) * 64 + c] = acc;
}

// ---------------- hw' = dinv * (h @ W) for both graphs ----------------

__global__ __launch_bounds__(256) void hw_kernel(const float* __restrict__ h,
        const float* __restrict__ Wp, const float* __restrict__ Wn,
        const float* __restrict__ dinvp, const float* __restrict__ dinvn,
        float* __restrict__ hwp, float* __restrict__ hwn, int n) {
    __shared__ __align__(16) float Wps[64 * 64];
    __shared__ __align__(16) float Wns[64 * 64];
    __shared__ __align__(16) float hs[4 * 64];
    int tid = threadIdx.x;
    for (int i = tid; i < 64 * 64; i += 256) { Wps[i] = Wp[i]; Wns[i] = Wn[i]; }
    long row = (long)blockIdx.x * 4;
    {
        int i = tid;
        long rr = row + (i >> 6);
        hs[i] = (rr < n) ? h[rr * 64 + (i & 63)] : 0.0f;
    }
    __syncthreads();
    int r = tid >> 6, c = tid & 63;
    float ap = 0.0f, an = 0.0f;
    #pragma unroll 4
    for (int k = 0; k < 64; k += 4) {
        float4 hv = *(const float4*)&hs[r * 64 + k];
        ap += hv.x*Wps[(k+0)*64+c] + hv.y*Wps[(k+1)*64+c] + hv.z*Wps[(k+2)*64+c] + hv.w*Wps[(k+3)*64+c];
        an += hv.x*Wns[(k+0)*64+c] + hv.y*Wns[(k+1)*64+c] + hv.z*Wns[(k+2)*64+c] + hv.w*Wns[(k+3)*64+c];
    }
    if (row + r < n) {
        hwp[(row + r) * 64 + c] = ap * dinvp[row + r];
        hwn[(row + r) * 64 + c] = an * dinvn[row + r];
    }
}

// ---------------- y0 init / scatter / finalize ----------------

__global__ __launch_bounds__(256) void y0_init_kernel(const float* __restrict__ hwp,
        const float* __restrict__ hwn, float* __restrict__ y0, int n) {
    long idx = (long)blockIdx.x * 256 + threadIdx.x;
    if (idx >= (long)n * 128) return;
    long i = idx >> 7; int c = (int)(idx & 127);
    y0[idx] = (c < 64) ? hwp[i * 64 + c] : hwn[i * 64 + (c - 64)];
}

__global__ __launch_bounds__(256) void scatter_kernel(const int* __restrict__ src,
        const int* __restrict__ dst, const float* __restrict__ hw,
        float* __restrict__ y0, int colOff, int nE) {
    int wid  = blockIdx.x * 4 + (threadIdx.x >> 6);
    int lane = threadIdx.x & 63;
    if (wid >= nE) return;
    int s = src[wid], d = dst[wid];
    atomicAdd(&y0[(long)d * 128 + colOff + lane], hw[(long)s * 64 + lane]);
}

__global__ __launch_bounds__(256) void finalize_kernel(float* __restrict__ y0,
        const float* __restrict__ dinvp, const float* __restrict__ dinvn,
        const float* __restrict__ bp, const float* __restrict__ bn, int n) {
    long idx = (long)blockIdx.x * 256 + threadIdx.x;
    if (idx >= (long)n * 128) return;
    long i = idx >> 7; int c = (int)(idx & 127);
    if (c < 64) y0[idx] = dinvp[i] * y0[idx] + bp[c];
    else        y0[idx] = dinvn[i] * y0[idx] + bn[c - 64];
}

// ---------------- fused dopri5 ODE, bf16 MFMA, A-reg-cache quad-split ----
// Block: 256 threads = 4 waves, ONE 16-row group. Wave w owns col-groups
// n in {2w, 2w+1}. Per MFMA (16x16x32, swapped operands, layout verified):
//   acc[r] (lane) = out[row = lane&15][c = n*16 + (lane>>4)*4 + r]
//   A-frag: Wt[n*16 + (lane&15)][kslice]  -> CACHED IN REGISTERS (af_g_k)
//   B-frag: yi[lane&15][kslice]           -> ds_read_b128 (needs all cols
//           -> per-stage barrier, dbuf'd yi aliased into Wt's 32KB)
// 256B rows, XOR-swizzle (l15&7)<<4.

#define MFMA_(A, B, C) __builtin_amdgcn_mfma_f32_16x16x32_bf16(A, B, C, 0, 0, 0)

#define ODE_STAGE(BUF, YIM, CONSM) {                                                \
    char* yr_ = (BUF) + rowoff;                                                     \
    uint2v pk_;                                                                     \
    pk_.x = cvt_pk(YIM(0,0), YIM(0,1)); pk_.y = cvt_pk(YIM(0,2), YIM(0,3));         \
    *(uint2v*)(yr_ + (g0off ^ swz)) = pk_;                                          \
    pk_.x = cvt_pk(YIM(1,0), YIM(1,1)); pk_.y = cvt_pk(YIM(1,2), YIM(1,3));         \
    *(uint2v*)(yr_ + (g1off ^ swz)) = pk_;                                          \
    __syncthreads();                                                                \
    short8v b0 = *(const short8v*)(yr_ + ((  0 + q16) ^ swz));                      \
    short8v b1 = *(const short8v*)(yr_ + (( 64 + q16) ^ swz));                      \
    short8v b2 = *(const short8v*)(yr_ + ((128 + q16) ^ swz));                      \
    short8v b3 = *(const short8v*)(yr_ + ((192 + q16) ^ swz));                      \
    {                                                                               \
        f32x4 a = bias0;                                                            \
        a = MFMA_(af00, b0, a); a = MFMA_(af01, b1, a);                             \
        a = MFMA_(af02, b2, a); a = MFMA_(af03, b3, a);                             \
        CONSM(0, fast_tanh(a[0]), fast_tanh(a[1]), fast_tanh(a[2]), fast_tanh(a[3])); \
    }                                                                               \
    {                                                                               \
        f32x4 a = bias1;                                                            \
        a = MFMA_(af10, b0, a); a = MFMA_(af11, b1, a);                             \
        a = MFMA_(af12, b2, a); a = MFMA_(af13, b3, a);                             \
        CONSM(1, fast_tanh(a[0]), fast_tanh(a[1]), fast_tanh(a[2]), fast_tanh(a[3])); \
    } }

#define YI1(nn, r) (y[nn][r])
#define YI2(nn, r) (y[nn][r] + hstep * (0.2f * KK(kp1,nn,r)))
#define YI3(nn, r) (y[nn][r] + hstep * (0.075f * KK(kp1,nn,r) + 0.225f * KK(kp2,nn,r)))
#define YI4(nn, r) (y[nn][r] + hstep * (0.9777777777777777f  * KK(kp1,nn,r) \
                                      - 3.7333333333333334f * KK(kp2,nn,r) \
                                      + 3.5555555555555554f * KK(kp3,nn,r)))
#define YI5(nn, r) (y[nn][r] + hstep * (2.9525986892242035f  * KK(kp1,nn,r) \
                                      - 11.595793324188385f * KK(kp2,nn,r) \
                                      + 9.822892851699436f  * KK(kp3,nn,r) \
                                      - 0.2908093278463649f * KK(kp4,nn,r)))
#define YI6(nn, r) (y[nn][r] + hstep * (2.8462752525252526f  * KK(kp1,nn,r) \
                                      - 10.757575757575758f * KK(kp2,nn,r) \
                                      + 8.906422717743473f  * KK(kp3,nn,r) \
                                      + 0.2784090909090909f * KK(kp4,nn,r) \
                                      - 0.2735313036020583f * KK(kp5,nn,r)))

#define CONS1(nn,t0,t1,t2,t3) { kp1[(nn)*2] = cvt_pk(t0,t1); kp1[(nn)*2+1] = cvt_pk(t2,t3); }
#define CONS2(nn,t0,t1,t2,t3) { kp2[(nn)*2] = cvt_pk(t0,t1); kp2[(nn)*2+1] = cvt_pk(t2,t3); }
#define CONS3(nn,t0,t1,t2,t3) { kp3[(nn)*2] = cvt_pk(t0,t1); kp3[(nn)*2+1] = cvt_pk(t2,t3); }
#define CONS4(nn,t0,t1,t2,t3) { kp4[(nn)*2] = cvt_pk(t0,t1); kp4[(nn)*2+1] = cvt_pk(t2,t3); }
#define CONS5(nn,t0,t1,t2,t3) { kp5[(nn)*2] = cvt_pk(t0,t1); kp5[(nn)*2+1] = cvt_pk(t2,t3); }
#define CONS6(nn,t0,t1,t2,t3) {                                             \
    y[nn][0] += hstep * (0.09114583333333333f * KK(kp1,nn,0)                \
                       + 0.44923629829290207f * KK(kp3,nn,0)                \
                       + 0.6510416666666666f  * KK(kp4,nn,0)                \
                       - 0.322376179245283f   * KK(kp5,nn,0)                \
                       + 0.13095238095238096f * (t0));                      \
    y[nn][1] += hstep * (0.09114583333333333f * KK(kp1,nn,1)                \
                       + 0.44923629829290207f * KK(kp3,nn,1)                \
                       + 0.6510416666666666f  * KK(kp4,nn,1)                \
                       - 0.322376179245283f   * KK(kp5,nn,1)                \
                       + 0.13095238095238096f * (t1));                      \
    y[nn][2] += hstep * (0.09114583333333333f * KK(kp1,nn,2)                \
                       + 0.44923629829290207f * KK(kp3,nn,2)                \
                       + 0.6510416666666666f  * KK(kp4,nn,2)                \
                       - 0.322376179245283f   * KK(kp5,nn,2)                \
                       + 0.13095238095238096f * (t2));                      \
    y[nn][3] += hstep * (0.09114583333333333f * KK(kp1,nn,3)                \
                       + 0.44923629829290207f * KK(kp3,nn,3)                \
                       + 0.6510416666666666f  * KK(kp4,nn,3)                \
                       - 0.322376179245283f   * KK(kp5,nn,3)                \
                       + 0.13095238095238096f * (t3)); }

__global__ __launch_bounds__(256) void ode_mfma_kernel(const float* __restrict__ y0,
        float* __restrict__ out, const float* __restrict__ W,
        const float* __restrict__ bb, const float* __restrict__ tt, int nrows) {
    // 32KB total: Wt lives here during prologue only; after A-frags are
    // cached in registers, the first 8KB is reused as yi double-buffers.
    __shared__ __align__(16) char smem[32768];
    int tid  = threadIdx.x;
    int lane = tid & 63, w = tid >> 6;       // w in {0..3}: col-group pair 2w,2w+1
    int l15 = lane & 15, q = lane >> 4;
    int swz = (lane & 7) << 4, q16 = q * 16, q8 = q * 8;
    int rowoff = l15 * 256;
    int g0off = w * 64 + q8, g1off = w * 64 + 32 + q8;

    // stage W^T (bf16, swizzled): Wt[c][d] = W[d][c]
    for (int i = tid; i < 16384; i += 256) {
        int d = i >> 7, c = i & 127;
        unsigned short hb = (unsigned short)bf16r(W[i]);
        *(unsigned short*)(smem + c * 256 + ((d * 2) ^ ((c & 7) << 4))) = hb;
    }
    __syncthreads();

    // cache my 8 A-fragments (2 col-groups x 4 k-slices) in registers
    const char* ab0 = smem + ((2 * w) * 16 + l15) * 256;
    const char* ab1 = smem + ((2 * w + 1) * 16 + l15) * 256;
    short8v af00 = *(const short8v*)(ab0 + ((  0 + q16) ^ swz));
    short8v af01 = *(const short8v*)(ab0 + (( 64 + q16) ^ swz));
    short8v af02 = *(const short8v*)(ab0 + ((128 + q16) ^ swz));
    short8v af03 = *(const short8v*)(ab0 + ((192 + q16) ^ swz));
    short8v af10 = *(const short8v*)(ab1 + ((  0 + q16) ^ swz));
    short8v af11 = *(const short8v*)(ab1 + (( 64 + q16) ^ swz));
    short8v af12 = *(const short8v*)(ab1 + ((128 + q16) ^ swz));
    short8v af13 = *(const short8v*)(ab1 + ((192 + q16) ^ swz));
    __syncthreads();   // all A-frags cached -> first 8KB may be clobbered

    float hstep = (tt[1] - tt[0]) * 0.03125f;

    // bias (unpacked f32) for my 2 col-groups: c = (2w+g)*16 + q*4 + r
    f32x4 bias0 = *(const f32x4*)&bb[(2 * w)     * 16 + q * 4];
    f32x4 bias1 = *(const f32x4*)&bb[(2 * w + 1) * 16 + q * 4];

    long grow = (long)blockIdx.x * 16 + l15;
    bool ok = grow < nrows;

    f32x4 y[2];
    if (ok) {
        y[0] = *(const f32x4*)&y0[grow * 128 + (2 * w)     * 16 + q * 4];
        y[1] = *(const f32x4*)&y0[grow * 128 + (2 * w + 1) * 16 + q * 4];
    } else {
        y[0] = (f32x4){0.0f, 0.0f, 0.0f, 0.0f};
        y[1] = (f32x4){0.0f, 0.0f, 0.0f, 0.0f};
    }

    char* bufA = smem;          // 16 rows x 256B = 4KB
    char* bufB = smem + 4096;   // double buffer

    unsigned kp1[4], kp2[4], kp3[4], kp4[4], kp5[4];

    #pragma unroll 1
    for (int step = 0; step < 32; ++step) {
        ODE_STAGE(bufA, YI1, CONS1);   // k1 = f(y)
        ODE_STAGE(bufB, YI2, CONS2);
        ODE_STAGE(bufA, YI3, CONS3);
        ODE_STAGE(bufB, YI4, CONS4);
        ODE_STAGE(bufA, YI5, CONS5);
        ODE_STAGE(bufB, YI6, CONS6);   // k6 folded into 5th-order y-update
    }

    if (ok) {
        *(f32x4*)&out[grow * 128 + (2 * w)     * 16 + q * 4] = y[0];
        *(f32x4*)&out[grow * 128 + (2 * w + 1) * 16 + q * 4] = y[1];
    }
}

// ---------------------------------------------------------------------------

extern "C" void kernel_launch(void* const* d_in, const int* in_sizes, int n_in,
                              void* d_out, int out_size, void* d_ws, size_t ws_size,
                              hipStream_t stream) {
    const float* x     = (const float*)d_in[0];
    const int*   pei   = (const int*)d_in[1];
    const int*   nei   = (const int*)d_in[2];
    const float* t     = (const float*)d_in[3];
    const float* W_enc = (const float*)d_in[4];
    const float* b_enc = (const float*)d_in[5];
    const float* W_pos = (const float*)d_in[6];
    const float* b_pos = (const float*)d_in[7];
    const float* W_neg = (const float*)d_in[8];
    const float* b_neg = (const float*)d_in[9];
    const float* W_ode = (const float*)d_in[10];
    const float* b_ode = (const float*)d_in[11];

    int n  = in_sizes[0] / 128;   // 50000 nodes
    int nE = in_sizes[1] / 2;     // 800000 edges

    // workspace layout (floats): h[n*64] | y0[n*128] | dinvp[n] | dinvn[n]
    float* ws    = (float*)d_ws;
    float* h     = ws;
    float* y0    = ws + (long)n * 64;
    float* dinvp = y0 + (long)n * 128;
    float* dinvn = dinvp + n;

    // d_out doubles as scratch for hw' (pos half then neg half), overwritten by ODE
    float* hwp = (float*)d_out;
    float* hwn = hwp + (long)n * 64;

    const int* psrc = pei;       const int* pdst = pei + nE;
    const int* nsrc = nei;       const int* ndst = nei + nE;

    int nbN  = (n + 255) / 256;
    int nbE  = (nE + 255) / 256;
    int nbR  = (n + 3) / 4;
    long tot = (long)n * 128;
    int nbT  = (int)((tot + 255) / 256);

    deg_init_kernel <<<nbN, 256, 0, stream>>>(dinvp, dinvn, n);
    deg_count_kernel<<<nbE, 256, 0, stream>>>(pdst, ndst, dinvp, dinvn, nE);
    dinv_kernel     <<<nbN, 256, 0, stream>>>(dinvp, dinvn, n);
    encoder_kernel  <<<nbR, 256, 0, stream>>>(x, W_enc, b_enc, h, n);
    hw_kernel       <<<nbR, 256, 0, stream>>>(h, W_pos, W_neg, dinvp, dinvn, hwp, hwn, n);
    y0_init_kernel  <<<nbT, 256, 0, stream>>>(hwp, hwn, y0, n);
    scatter_kernel  <<<(nE + 3) / 4, 256, 0, stream>>>(psrc, pdst, hwp, y0, 0,  nE);
    scatter_kernel  <<<(nE + 3) / 4, 256, 0, stream>>>(nsrc, ndst, hwn, y0, 64, nE);
    finalize_kernel <<<nbT, 256, 0, stream>>>(y0, dinvp, dinvn, b_pos, b_neg, n);
    ode_mfma_kernel <<<(n + 15) / 16, 256, 0, stream>>>(y0, (float*)d_out, W_ode, b_ode, t, n);
}

// Round 15
// 1175.640 us; speedup vs baseline: 1.4161x; 1.0134x over previous
//
#include <hip/hip_runtime.h>
#include <hip/hip_bf16.h>

// ---------------------------------------------------------------------------
// DynamiSE: encoder GEMM -> 2x GCNConv (atomic scatter) -> fused dopri5 ODE.
// Round 15: un-pack the k-history (ODE is now VALU-bound: 79% busy @ r14).
//   - kp1..kp5 stored as f32 (f32x4[2] each, +40 VGPR; r14 used 64 of 128):
//     kills ~30 unpk ops/stage (KK) + 4 cvt_pk/stage (CONS), and the
//     y-update consumes unrounded f32 k values (strictly more accurate).
//   - hstep folded into Butcher coefficients once (c21=hstep*0.2, ...):
//     removes the per-element hstep multiply (8 ops/stage).
//   LDS/barrier/MFMA structure identical to r14 (A-frags reg-cached,
//   32KB aliased LDS, 5 blocks/CU). Front-end untouched.
// ---------------------------------------------------------------------------

typedef __attribute__((ext_vector_type(8))) short short8v;   // 8 bf16 = 4 VGPR
typedef __attribute__((ext_vector_type(4))) float f32x4;
typedef __attribute__((ext_vector_type(2))) unsigned uint2v;

__device__ __forceinline__ float fast_tanh(float x) {
    float e = __builtin_amdgcn_exp2f(x * 2.8853900817779268f);
    return 1.0f - 2.0f * __builtin_amdgcn_rcpf(e + 1.0f);
}

__device__ __forceinline__ unsigned bf16r(float x) {   // RTNE f32->bf16 bits
    unsigned u = __float_as_uint(x);
    return (u + 0x7fffu + ((u >> 16) & 1u)) >> 16;
}
__device__ __forceinline__ unsigned cvt_pk(float lo, float hi) {  // 1 VALU op
    unsigned r;
    asm("v_cvt_pk_bf16_f32 %0, %1, %2" : "=v"(r) : "v"(lo), "v"(hi));
    return r;
}

// ---------------- degree / dinv ----------------

__global__ __launch_bounds__(256) void deg_init_kernel(float* degp, float* degn, int n) {
    int i = blockIdx.x * 256 + threadIdx.x;
    if (i < n) { degp[i] = 1.0f; degn[i] = 1.0f; }
}

__global__ __launch_bounds__(256) void deg_count_kernel(const int* __restrict__ pdst,
        const int* __restrict__ ndst, float* degp, float* degn, int nE) {
    int e = blockIdx.x * 256 + threadIdx.x;
    if (e < nE) {
        atomicAdd(&degp[pdst[e]], 1.0f);
        atomicAdd(&degn[ndst[e]], 1.0f);
    }
}

__global__ __launch_bounds__(256) void dinv_kernel(float* degp, float* degn, int n) {
    int i = blockIdx.x * 256 + threadIdx.x;
    if (i < n) { degp[i] = rsqrtf(degp[i]); degn[i] = rsqrtf(degn[i]); }
}

// ---------------- encoder: h = x @ W_enc + b_enc ----------------

__global__ __launch_bounds__(256) void encoder_kernel(const float* __restrict__ x,
        const float* __restrict__ W, const float* __restrict__ b,
        float* __restrict__ h, int n) {
    __shared__ __align__(16) float Ws[128 * 64];
    __shared__ __align__(16) float xs[4 * 128];
    int tid = threadIdx.x;
    for (int i = tid; i < 128 * 64; i += 256) Ws[i] = W[i];
    long row = (long)blockIdx.x * 4;
    for (int i = tid; i < 4 * 128; i += 256) {
        long rr = row + (i >> 7);
        xs[i] = (rr < n) ? x[rr * 128 + (i & 127)] : 0.0f;
    }
    __syncthreads();
    int r = tid >> 6, c = tid & 63;
    float acc = b[c];
    #pragma unroll 8
    for (int k = 0; k < 128; k += 4) {
        float4 xv = *(const float4*)&xs[r * 128 + k];
        acc += xv.x * Ws[(k+0)*64+c] + xv.y * Ws[(k+1)*64+c]
             + xv.z * Ws[(k+2)*64+c] + xv.w * Ws[(k+3)*64+c];
    }
    if (row + r < n) h[(row + r) * 64 + c] = acc;
}

// ---------------- hw' = dinv * (h @ W) for both graphs ----------------

__global__ __launch_bounds__(256) void hw_kernel(const float* __restrict__ h,
        const float* __restrict__ Wp, const float* __restrict__ Wn,
        const float* __restrict__ dinvp, const float* __restrict__ dinvn,
        float* __restrict__ hwp, float* __restrict__ hwn, int n) {
    __shared__ __align__(16) float Wps[64 * 64];
    __shared__ __align__(16) float Wns[64 * 64];
    __shared__ __align__(16) float hs[4 * 64];
    int tid = threadIdx.x;
    for (int i = tid; i < 64 * 64; i += 256) { Wps[i] = Wp[i]; Wns[i] = Wn[i]; }
    long row = (long)blockIdx.x * 4;
    {
        int i = tid;
        long rr = row + (i >> 6);
        hs[i] = (rr < n) ? h[rr * 64 + (i & 63)] : 0.0f;
    }
    __syncthreads();
    int r = tid >> 6, c = tid & 63;
    float ap = 0.0f, an = 0.0f;
    #pragma unroll 4
    for (int k = 0; k < 64; k += 4) {
        float4 hv = *(const float4*)&hs[r * 64 + k];
        ap += hv.x*Wps[(k+0)*64+c] + hv.y*Wps[(k+1)*64+c] + hv.z*Wps[(k+2)*64+c] + hv.w*Wps[(k+3)*64+c];
        an += hv.x*Wns[(k+0)*64+c] + hv.y*Wns[(k+1)*64+c] + hv.z*Wns[(k+2)*64+c] + hv.w*Wns[(k+3)*64+c];
    }
    if (row + r < n) {
        hwp[(row + r) * 64 + c] = ap * dinvp[row + r];
        hwn[(row + r) * 64 + c] = an * dinvn[row + r];
    }
}

// ---------------- y0 init / scatter / finalize ----------------

__global__ __launch_bounds__(256) void y0_init_kernel(const float* __restrict__ hwp,
        const float* __restrict__ hwn, float* __restrict__ y0, int n) {
    long idx = (long)blockIdx.x * 256 + threadIdx.x;
    if (idx >= (long)n * 128) return;
    long i = idx >> 7; int c = (int)(idx & 127);
    y0[idx] = (c < 64) ? hwp[i * 64 + c] : hwn[i * 64 + (c - 64)];
}

__global__ __launch_bounds__(256) void scatter_kernel(const int* __restrict__ src,
        const int* __restrict__ dst, const float* __restrict__ hw,
        float* __restrict__ y0, int colOff, int nE) {
    int wid  = blockIdx.x * 4 + (threadIdx.x >> 6);
    int lane = threadIdx.x & 63;
    if (wid >= nE) return;
    int s = src[wid], d = dst[wid];
    atomicAdd(&y0[(long)d * 128 + colOff + lane], hw[(long)s * 64 + lane]);
}

__global__ __launch_bounds__(256) void finalize_kernel(float* __restrict__ y0,
        const float* __restrict__ dinvp, const float* __restrict__ dinvn,
        const float* __restrict__ bp, const float* __restrict__ bn, int n) {
    long idx = (long)blockIdx.x * 256 + threadIdx.x;
    if (idx >= (long)n * 128) return;
    long i = idx >> 7; int c = (int)(idx & 127);
    if (c < 64) y0[idx] = dinvp[i] * y0[idx] + bp[c];
    else        y0[idx] = dinvn[i] * y0[idx] + bn[c - 64];
}

// ---------------- fused dopri5 ODE, bf16 MFMA, A-reg-cache quad-split ----
// Block: 256 threads = 4 waves, ONE 16-row group. Wave w owns col-groups
// n in {2w, 2w+1}. Per MFMA (16x16x32, swapped operands, layout verified):
//   acc[r] (lane) = out[row = lane&15][c = n*16 + (lane>>4)*4 + r]
//   A-frag: Wt[n*16 + (lane&15)][kslice]  -> CACHED IN REGISTERS
//   B-frag: yi[lane&15][kslice]           -> ds_read_b128 (needs all cols
//           -> per-stage barrier, dbuf'd yi aliased into Wt's 32KB)
// 256B rows, XOR-swizzle (l15&7)<<4. k-history kept in f32 registers.

#define MFMA_(A, B, C) __builtin_amdgcn_mfma_f32_16x16x32_bf16(A, B, C, 0, 0, 0)

#define ODE_STAGE(BUF, YIM, CONSM) {                                                \
    char* yr_ = (BUF) + rowoff;                                                     \
    uint2v pk_;                                                                     \
    pk_.x = cvt_pk(YIM(0,0), YIM(0,1)); pk_.y = cvt_pk(YIM(0,2), YIM(0,3));         \
    *(uint2v*)(yr_ + (g0off ^ swz)) = pk_;                                          \
    pk_.x = cvt_pk(YIM(1,0), YIM(1,1)); pk_.y = cvt_pk(YIM(1,2), YIM(1,3));         \
    *(uint2v*)(yr_ + (g1off ^ swz)) = pk_;                                          \
    __syncthreads();                                                                \
    short8v b0 = *(const short8v*)(yr_ + ((  0 + q16) ^ swz));                      \
    short8v b1 = *(const short8v*)(yr_ + (( 64 + q16) ^ swz));                      \
    short8v b2 = *(const short8v*)(yr_ + ((128 + q16) ^ swz));                      \
    short8v b3 = *(const short8v*)(yr_ + ((192 + q16) ^ swz));                      \
    {                                                                               \
        f32x4 a = bias0;                                                            \
        a = MFMA_(af00, b0, a); a = MFMA_(af01, b1, a);                             \
        a = MFMA_(af02, b2, a); a = MFMA_(af03, b3, a);                             \
        CONSM(0, fast_tanh(a[0]), fast_tanh(a[1]), fast_tanh(a[2]), fast_tanh(a[3])); \
    }                                                                               \
    {                                                                               \
        f32x4 a = bias1;                                                            \
        a = MFMA_(af10, b0, a); a = MFMA_(af11, b1, a);                             \
        a = MFMA_(af12, b2, a); a = MFMA_(af13, b3, a);                             \
        CONSM(1, fast_tanh(a[0]), fast_tanh(a[1]), fast_tanh(a[2]), fast_tanh(a[3])); \
    } }

// yi formulas: hstep pre-folded into c** coefficients (computed once below)
#define YI1(nn, r) (y[nn][r])
#define YI2(nn, r) (y[nn][r] + c21 * kp1[nn][r])
#define YI3(nn, r) (y[nn][r] + c31 * kp1[nn][r] + c32 * kp2[nn][r])
#define YI4(nn, r) (y[nn][r] + c41 * kp1[nn][r] + c42 * kp2[nn][r] + c43 * kp3[nn][r])
#define YI5(nn, r) (y[nn][r] + c51 * kp1[nn][r] + c52 * kp2[nn][r] + c53 * kp3[nn][r] \
                             + c54 * kp4[nn][r])
#define YI6(nn, r) (y[nn][r] + c61 * kp1[nn][r] + c62 * kp2[nn][r] + c63 * kp3[nn][r] \
                             + c64 * kp4[nn][r] + c65 * kp5[nn][r])

#define CONS1(nn,t0,t1,t2,t3) { kp1[nn][0]=t0; kp1[nn][1]=t1; kp1[nn][2]=t2; kp1[nn][3]=t3; }
#define CONS2(nn,t0,t1,t2,t3) { kp2[nn][0]=t0; kp2[nn][1]=t1; kp2[nn][2]=t2; kp2[nn][3]=t3; }
#define CONS3(nn,t0,t1,t2,t3) { kp3[nn][0]=t0; kp3[nn][1]=t1; kp3[nn][2]=t2; kp3[nn][3]=t3; }
#define CONS4(nn,t0,t1,t2,t3) { kp4[nn][0]=t0; kp4[nn][1]=t1; kp4[nn][2]=t2; kp4[nn][3]=t3; }
#define CONS5(nn,t0,t1,t2,t3) { kp5[nn][0]=t0; kp5[nn][1]=t1; kp5[nn][2]=t2; kp5[nn][3]=t3; }
#define CONS6(nn,t0,t1,t2,t3) {                                             \
    y[nn][0] += d1 * kp1[nn][0] + d3 * kp3[nn][0] + d4 * kp4[nn][0]         \
              + d5 * kp5[nn][0] + d6 * (t0);                                \
    y[nn][1] += d1 * kp1[nn][1] + d3 * kp3[nn][1] + d4 * kp4[nn][1]         \
              + d5 * kp5[nn][1] + d6 * (t1);                                \
    y[nn][2] += d1 * kp1[nn][2] + d3 * kp3[nn][2] + d4 * kp4[nn][2]         \
              + d5 * kp5[nn][2] + d6 * (t2);                                \
    y[nn][3] += d1 * kp1[nn][3] + d3 * kp3[nn][3] + d4 * kp4[nn][3]         \
              + d5 * kp5[nn][3] + d6 * (t3); }

__global__ __launch_bounds__(256) void ode_mfma_kernel(const float* __restrict__ y0,
        float* __restrict__ out, const float* __restrict__ W,
        const float* __restrict__ bb, const float* __restrict__ tt, int nrows) {
    // 32KB total: Wt lives here during prologue only; after A-frags are
    // cached in registers, the first 8KB is reused as yi double-buffers.
    __shared__ __align__(16) char smem[32768];
    int tid  = threadIdx.x;
    int lane = tid & 63, w = tid >> 6;       // w in {0..3}: col-group pair 2w,2w+1
    int l15 = lane & 15, q = lane >> 4;
    int swz = (lane & 7) << 4, q16 = q * 16, q8 = q * 8;
    int rowoff = l15 * 256;
    int g0off = w * 64 + q8, g1off = w * 64 + 32 + q8;

    // stage W^T (bf16, swizzled): Wt[c][d] = W[d][c]
    for (int i = tid; i < 16384; i += 256) {
        int d = i >> 7, c = i & 127;
        unsigned short hb = (unsigned short)bf16r(W[i]);
        *(unsigned short*)(smem + c * 256 + ((d * 2) ^ ((c & 7) << 4))) = hb;
    }
    __syncthreads();

    // cache my 8 A-fragments (2 col-groups x 4 k-slices) in registers
    const char* ab0 = smem + ((2 * w) * 16 + l15) * 256;
    const char* ab1 = smem + ((2 * w + 1) * 16 + l15) * 256;
    short8v af00 = *(const short8v*)(ab0 + ((  0 + q16) ^ swz));
    short8v af01 = *(const short8v*)(ab0 + (( 64 + q16) ^ swz));
    short8v af02 = *(const short8v*)(ab0 + ((128 + q16) ^ swz));
    short8v af03 = *(const short8v*)(ab0 + ((192 + q16) ^ swz));
    short8v af10 = *(const short8v*)(ab1 + ((  0 + q16) ^ swz));
    short8v af11 = *(const short8v*)(ab1 + (( 64 + q16) ^ swz));
    short8v af12 = *(const short8v*)(ab1 + ((128 + q16) ^ swz));
    short8v af13 = *(const short8v*)(ab1 + ((192 + q16) ^ swz));
    __syncthreads();   // all A-frags cached -> first 8KB may be clobbered

    float hstep = (tt[1] - tt[0]) * 0.03125f;
    // Butcher coefficients with hstep folded in (uniform -> SGPRs)
    float c21 = hstep * 0.2f;
    float c31 = hstep * 0.075f,               c32 = hstep * 0.225f;
    float c41 = hstep * 0.9777777777777777f,  c42 = hstep * -3.7333333333333334f,
          c43 = hstep * 3.5555555555555554f;
    float c51 = hstep * 2.9525986892242035f,  c52 = hstep * -11.595793324188385f,
          c53 = hstep * 9.822892851699436f,   c54 = hstep * -0.2908093278463649f;
    float c61 = hstep * 2.8462752525252526f,  c62 = hstep * -10.757575757575758f,
          c63 = hstep * 8.906422717743473f,   c64 = hstep * 0.2784090909090909f,
          c65 = hstep * -0.2735313036020583f;
    float d1 = hstep * 0.09114583333333333f,  d3 = hstep * 0.44923629829290207f,
          d4 = hstep * 0.6510416666666666f,   d5 = hstep * -0.322376179245283f,
          d6 = hstep * 0.13095238095238096f;

    // bias (unpacked f32) for my 2 col-groups: c = (2w+g)*16 + q*4 + r
    f32x4 bias0 = *(const f32x4*)&bb[(2 * w)     * 16 + q * 4];
    f32x4 bias1 = *(const f32x4*)&bb[(2 * w + 1) * 16 + q * 4];

    long grow = (long)blockIdx.x * 16 + l15;
    bool ok = grow < nrows;

    f32x4 y[2];
    if (ok) {
        y[0] = *(const f32x4*)&y0[grow * 128 + (2 * w)     * 16 + q * 4];
        y[1] = *(const f32x4*)&y0[grow * 128 + (2 * w + 1) * 16 + q * 4];
    } else {
        y[0] = (f32x4){0.0f, 0.0f, 0.0f, 0.0f};
        y[1] = (f32x4){0.0f, 0.0f, 0.0f, 0.0f};
    }

    char* bufA = smem;          // 16 rows x 256B = 4KB
    char* bufB = smem + 4096;   // double buffer

    f32x4 kp1[2], kp2[2], kp3[2], kp4[2], kp5[2];   // f32 k-history, ~40 VGPR

    #pragma unroll 1
    for (int step = 0; step < 32; ++step) {
        ODE_STAGE(bufA, YI1, CONS1);   // k1 = f(y)
        ODE_STAGE(bufB, YI2, CONS2);
        ODE_STAGE(bufA, YI3, CONS3);
        ODE_STAGE(bufB, YI4, CONS4);
        ODE_STAGE(bufA, YI5, CONS5);
        ODE_STAGE(bufB, YI6, CONS6);   // k6 folded into 5th-order y-update
    }

    if (ok) {
        *(f32x4*)&out[grow * 128 + (2 * w)     * 16 + q * 4] = y[0];
        *(f32x4*)&out[grow * 128 + (2 * w + 1) * 16 + q * 4] = y[1];
    }
}

// ---------------------------------------------------------------------------

extern "C" void kernel_launch(void* const* d_in, const int* in_sizes, int n_in,
                              void* d_out, int out_size, void* d_ws, size_t ws_size,
                              hipStream_t stream) {
    const float* x     = (const float*)d_in[0];
    const int*   pei   = (const int*)d_in[1];
    const int*   nei   = (const int*)d_in[2];
    const float* t     = (const float*)d_in[3];
    const float* W_enc = (const float*)d_in[4];
    const float* b_enc = (const float*)d_in[5];
    const float* W_pos = (const float*)d_in[6];
    const float* b_pos = (const float*)d_in[7];
    const float* W_neg = (const float*)d_in[8];
    const float* b_neg = (const float*)d_in[9];
    const float* W_ode = (const float*)d_in[10];
    const float* b_ode = (const float*)d_in[11];

    int n  = in_sizes[0] / 128;   // 50000 nodes
    int nE = in_sizes[1] / 2;     // 800000 edges

    // workspace layout (floats): h[n*64] | y0[n*128] | dinvp[n] | dinvn[n]
    float* ws    = (float*)d_ws;
    float* h     = ws;
    float* y0    = ws + (long)n * 64;
    float* dinvp = y0 + (long)n * 128;
    float* dinvn = dinvp + n;

    // d_out doubles as scratch for hw' (pos half then neg half), overwritten by ODE
    float* hwp = (float*)d_out;
    float* hwn = hwp + (long)n * 64;

    const int* psrc = pei;       const int* pdst = pei + nE;
    const int* nsrc = nei;       const int* ndst = nei + nE;

    int nbN  = (n + 255) / 256;
    int nbE  = (nE + 255) / 256;
    int nbR  = (n + 3) / 4;
    long tot = (long)n * 128;
    int nbT  = (int)((tot + 255) / 256);

    deg_init_kernel <<<nbN, 256, 0, stream>>>(dinvp, dinvn, n);
    deg_count_kernel<<<nbE, 256, 0, stream>>>(pdst, ndst, dinvp, dinvn, nE);
    dinv_kernel     <<<nbN, 256, 0, stream>>>(dinvp, dinvn, n);
    encoder_kernel  <<<nbR, 256, 0, stream>>>(x, W_enc, b_enc, h, n);
    hw_kernel       <<<nbR, 256, 0, stream>>>(h, W_pos, W_neg, dinvp, dinvn, hwp, hwn, n);
    y0_init_kernel  <<<nbT, 256, 0, stream>>>(hwp, hwn, y0, n);
    scatter_kernel  <<<(nE + 3) / 4, 256, 0, stream>>>(psrc, pdst, hwp, y0, 0,  nE);
    scatter_kernel  <<<(nE + 3) / 4, 256, 0, stream>>>(nsrc, ndst, hwn, y0, 64, nE);
    finalize_kernel <<<nbT, 256, 0, stream>>>(y0, dinvp, dinvn, b_pos, b_neg, n);
    ode_mfma_kernel <<<(n + 15) / 16, 256, 0, stream>>>(y0, (float*)d_out, W_ode, b_ode, t, n);
}

// Round 18
// 1074.123 us; speedup vs baseline: 1.5500x; 1.0945x over previous
//
#include <hip/hip_runtime.h>
#include <hip/hip_bf16.h>

// ---------------------------------------------------------------------------
// DynamiSE: encoder GEMM -> 2x GCNConv -> fused dopri5 ODE.
// Round 18 = round-16/17 resubmit (both benches were infra flakes; container
// died before source push). Kill the scatter atomics (front-end ~467us of
// 1176; the two scatter kernels do 102M random f32 atomicAdds). CSR gather:
//   count (int atomics) -> scan (2-block kernel; also emits dinv, zeroes
//   cursors) -> fill src-lists (int atomics) -> aggregate (1 wave/node,
//   coalesced hw-row gather, fuses y0_init+scatter+finalize, ZERO f32
//   atomics). dinv applied per-edge in the gather (so hw_kernel no longer
//   needs it -> CSR arrays live in the DEAD h region; ws unchanged).
// ODE kernel identical to r15 (709us).
// ---------------------------------------------------------------------------

typedef __attribute__((ext_vector_type(8))) short short8v;   // 8 bf16 = 4 VGPR
typedef __attribute__((ext_vector_type(4))) float f32x4;
typedef __attribute__((ext_vector_type(2))) unsigned uint2v;

__device__ __forceinline__ float fast_tanh(float x) {
    float e = __builtin_amdgcn_exp2f(x * 2.8853900817779268f);
    return 1.0f - 2.0f * __builtin_amdgcn_rcpf(e + 1.0f);
}

__device__ __forceinline__ unsigned bf16r(float x) {   // RTNE f32->bf16 bits
    unsigned u = __float_as_uint(x);
    return (u + 0x7fffu + ((u >> 16) & 1u)) >> 16;
}
__device__ __forceinline__ unsigned cvt_pk(float lo, float hi) {  // 1 VALU op
    unsigned r;
    asm("v_cvt_pk_bf16_f32 %0, %1, %2" : "=v"(r) : "v"(lo), "v"(hi));
    return r;
}

// ---------------- encoder: h = x @ W_enc + b_enc ----------------

__global__ __launch_bounds__(256) void encoder_kernel(const float* __restrict__ x,
        const float* __restrict__ W, const float* __restrict__ b,
        float* __restrict__ h, int n) {
    __shared__ __align__(16) float Ws[128 * 64];
    __shared__ __align__(16) float xs[4 * 128];
    int tid = threadIdx.x;
    for (int i = tid; i < 128 * 64; i += 256) Ws[i] = W[i];
    long row = (long)blockIdx.x * 4;
    for (int i = tid; i < 4 * 128; i += 256) {
        long rr = row + (i >> 7);
        xs[i] = (rr < n) ? x[rr * 128 + (i & 127)] : 0.0f;
    }
    __syncthreads();
    int r = tid >> 6, c = tid & 63;
    float acc = b[c];
    #pragma unroll 8
    for (int k = 0; k < 128; k += 4) {
        float4 xv = *(const float4*)&xs[r * 128 + k];
        acc += xv.x * Ws[(k+0)*64+c] + xv.y * Ws[(k+1)*64+c]
             + xv.z * Ws[(k+2)*64+c] + xv.w * Ws[(k+3)*64+c];
    }
    if (row + r < n) h[(row + r) * 64 + c] = acc;
}

// ---------------- hw = h @ W for both graphs (no dinv here) ----------------

__global__ __launch_bounds__(256) void hw_kernel(const float* __restrict__ h,
        const float* __restrict__ Wp, const float* __restrict__ Wn,
        float* __restrict__ hwp, float* __restrict__ hwn, int n) {
    __shared__ __align__(16) float Wps[64 * 64];
    __shared__ __align__(16) float Wns[64 * 64];
    __shared__ __align__(16) float hs[4 * 64];
    int tid = threadIdx.x;
    for (int i = tid; i < 64 * 64; i += 256) { Wps[i] = Wp[i]; Wns[i] = Wn[i]; }
    long row = (long)blockIdx.x * 4;
    {
        int i = tid;
        long rr = row + (i >> 6);
        hs[i] = (rr < n) ? h[rr * 64 + (i & 63)] : 0.0f;
    }
    __syncthreads();
    int r = tid >> 6, c = tid & 63;
    float ap = 0.0f, an = 0.0f;
    #pragma unroll 4
    for (int k = 0; k < 64; k += 4) {
        float4 hv = *(const float4*)&hs[r * 64 + k];
        ap += hv.x*Wps[(k+0)*64+c] + hv.y*Wps[(k+1)*64+c] + hv.z*Wps[(k+2)*64+c] + hv.w*Wps[(k+3)*64+c];
        an += hv.x*Wns[(k+0)*64+c] + hv.y*Wns[(k+1)*64+c] + hv.z*Wns[(k+2)*64+c] + hv.w*Wns[(k+3)*64+c];
    }
    if (row + r < n) {
        hwp[(row + r) * 64 + c] = ap;
        hwn[(row + r) * 64 + c] = an;
    }
}

// ---------------- CSR build: zero / count / scan / fill ----------------

__global__ __launch_bounds__(256) void cnt_zero_kernel(int* cntp, int* cntn, int n) {
    int i = blockIdx.x * 256 + threadIdx.x;
    if (i < n) { cntp[i] = 0; cntn[i] = 0; }
}

__global__ __launch_bounds__(256) void count_kernel(const int* __restrict__ pdst,
        const int* __restrict__ ndst, int* cntp, int* cntn, int nE) {
    int e = blockIdx.x * 256 + threadIdx.x;
    if (e < nE) {
        atomicAdd(&cntp[pdst[e]], 1);
        atomicAdd(&cntn[ndst[e]], 1);
    }
}

// grid = 2 blocks (0: pos, 1: neg), 1024 threads. Exclusive scan cnt->rowptr,
// dinv = rsqrt(cnt+1) (self-loop), cnt zeroed for reuse as fill cursor.
__global__ __launch_bounds__(1024) void scan_kernel(int* cntp, int* cntn,
        int* rpp, int* rpn, float* dinvp, float* dinvn, int n) {
    int* cnt  = blockIdx.x ? cntn  : cntp;
    int* rp   = blockIdx.x ? rpn   : rpp;
    float* dv = blockIdx.x ? dinvn : dinvp;
    __shared__ int ps[1024];
    int t = threadIdx.x;
    int CH = (n + 1023) / 1024;
    int beg = t * CH, end = beg + CH; if (end > n) end = n;
    int s = 0;
    for (int i = beg; i < end && i >= 0; ++i) s += cnt[i];
    ps[t] = s;
    __syncthreads();
    for (int off = 1; off < 1024; off <<= 1) {
        int v = (t >= off) ? ps[t - off] : 0;
        __syncthreads();
        ps[t] += v;
        __syncthreads();
    }
    int run = (t == 0) ? 0 : ps[t - 1];
    for (int i = beg; i < end && i >= 0; ++i) {
        int c = cnt[i];
        rp[i] = run; run += c;
        dv[i] = rsqrtf((float)c + 1.0f);
        cnt[i] = 0;
    }
    if (t == 1023) rp[n] = ps[1023];
}

__global__ __launch_bounds__(256) void fill_kernel(const int* __restrict__ src,
        const int* __restrict__ dst, const int* __restrict__ rp,
        int* cur, int* outarr, int nE) {
    int e = blockIdx.x * 256 + threadIdx.x;
    if (e >= nE) return;
    int d = dst[e];
    int pos = rp[d] + atomicAdd(&cur[d], 1);
    outarr[pos] = src[e];
}

// ---------------- gather aggregate: y0 = dinv_d*(sum + dinv_d*hw_d) + b ----
// One wave per node; lane = column. Zero float atomics; coalesced 256B reads.

__global__ __launch_bounds__(256) void aggregate_kernel(
        const float* __restrict__ hwp, const float* __restrict__ hwn,
        const int* __restrict__ srcp, const int* __restrict__ srcn,
        const int* __restrict__ rpp, const int* __restrict__ rpn,
        const float* __restrict__ dinvp, const float* __restrict__ dinvn,
        const float* __restrict__ bp, const float* __restrict__ bn,
        float* __restrict__ y0, int n) {
    int w = threadIdx.x >> 6, lane = threadIdx.x & 63;
    int d = blockIdx.x * 4 + w;
    if (d >= n) return;
    {   // positive graph -> cols [0,64)
        int beg = rpp[d], end = rpp[d + 1];
        float s0 = 0, s1 = 0, s2 = 0, s3 = 0;
        int i = beg;
        for (; i + 4 <= end; i += 4) {
            int a0 = srcp[i], a1 = srcp[i+1], a2 = srcp[i+2], a3 = srcp[i+3];
            s0 += dinvp[a0] * hwp[(long)a0 * 64 + lane];
            s1 += dinvp[a1] * hwp[(long)a1 * 64 + lane];
            s2 += dinvp[a2] * hwp[(long)a2 * 64 + lane];
            s3 += dinvp[a3] * hwp[(long)a3 * 64 + lane];
        }
        for (; i < end; ++i) {
            int a0 = srcp[i];
            s0 += dinvp[a0] * hwp[(long)a0 * 64 + lane];
        }
        float dv = dinvp[d];
        float sum = (s0 + s1) + (s2 + s3) + dv * hwp[(long)d * 64 + lane];
        y0[(long)d * 128 + lane] = dv * sum + bp[lane];
    }
    {   // negative graph -> cols [64,128)
        int beg = rpn[d], end = rpn[d + 1];
        float s0 = 0, s1 = 0, s2 = 0, s3 = 0;
        int i = beg;
        for (; i + 4 <= end; i += 4) {
            int a0 = srcn[i], a1 = srcn[i+1], a2 = srcn[i+2], a3 = srcn[i+3];
            s0 += dinvn[a0] * hwn[(long)a0 * 64 + lane];
            s1 += dinvn[a1] * hwn[(long)a1 * 64 + lane];
            s2 += dinvn[a2] * hwn[(long)a2 * 64 + lane];
            s3 += dinvn[a3] * hwn[(long)a3 * 64 + lane];
        }
        for (; i < end; ++i) {
            int a0 = srcn[i];
            s0 += dinvn[a0] * hwn[(long)a0 * 64 + lane];
        }
        float dv = dinvn[d];
        float sum = (s0 + s1) + (s2 + s3) + dv * hwn[(long)d * 64 + lane];
        y0[(long)d * 128 + 64 + lane] = dv * sum + bn[lane];
    }
}

// ---------------- fused dopri5 ODE, bf16 MFMA (identical to r15) ----------

#define MFMA_(A, B, C) __builtin_amdgcn_mfma_f32_16x16x32_bf16(A, B, C, 0, 0, 0)

#define ODE_STAGE(BUF, YIM, CONSM) {                                                \
    char* yr_ = (BUF) + rowoff;                                                     \
    uint2v pk_;                                                                     \
    pk_.x = cvt_pk(YIM(0,0), YIM(0,1)); pk_.y = cvt_pk(YIM(0,2), YIM(0,3));         \
    *(uint2v*)(yr_ + (g0off ^ swz)) = pk_;                                          \
    pk_.x = cvt_pk(YIM(1,0), YIM(1,1)); pk_.y = cvt_pk(YIM(1,2), YIM(1,3));         \
    *(uint2v*)(yr_ + (g1off ^ swz)) = pk_;                                          \
    __syncthreads();                                                                \
    short8v b0 = *(const short8v*)(yr_ + ((  0 + q16) ^ swz));                      \
    short8v b1 = *(const short8v*)(yr_ + (( 64 + q16) ^ swz));                      \
    short8v b2 = *(const short8v*)(yr_ + ((128 + q16) ^ swz));                      \
    short8v b3 = *(const short8v*)(yr_ + ((192 + q16) ^ swz));                      \
    {                                                                               \
        f32x4 a = bias0;                                                            \
        a = MFMA_(af00, b0, a); a = MFMA_(af01, b1, a);                             \
        a = MFMA_(af02, b2, a); a = MFMA_(af03, b3, a);                             \
        CONSM(0, fast_tanh(a[0]), fast_tanh(a[1]), fast_tanh(a[2]), fast_tanh(a[3])); \
    }                                                                               \
    {                                                                               \
        f32x4 a = bias1;                                                            \
        a = MFMA_(af10, b0, a); a = MFMA_(af11, b1, a);                             \
        a = MFMA_(af12, b2, a); a = MFMA_(af13, b3, a);                             \
        CONSM(1, fast_tanh(a[0]), fast_tanh(a[1]), fast_tanh(a[2]), fast_tanh(a[3])); \
    } }

#define YI1(nn, r) (y[nn][r])
#define YI2(nn, r) (y[nn][r] + c21 * kp1[nn][r])
#define YI3(nn, r) (y[nn][r] + c31 * kp1[nn][r] + c32 * kp2[nn][r])
#define YI4(nn, r) (y[nn][r] + c41 * kp1[nn][r] + c42 * kp2[nn][r] + c43 * kp3[nn][r])
#define YI5(nn, r) (y[nn][r] + c51 * kp1[nn][r] + c52 * kp2[nn][r] + c53 * kp3[nn][r] \
                             + c54 * kp4[nn][r])
#define YI6(nn, r) (y[nn][r] + c61 * kp1[nn][r] + c62 * kp2[nn][r] + c63 * kp3[nn][r] \
                             + c64 * kp4[nn][r] + c65 * kp5[nn][r])

#define CONS1(nn,t0,t1,t2,t3) { kp1[nn][0]=t0; kp1[nn][1]=t1; kp1[nn][2]=t2; kp1[nn][3]=t3; }
#define CONS2(nn,t0,t1,t2,t3) { kp2[nn][0]=t0; kp2[nn][1]=t1; kp2[nn][2]=t2; kp2[nn][3]=t3; }
#define CONS3(nn,t0,t1,t2,t3) { kp3[nn][0]=t0; kp3[nn][1]=t1; kp3[nn][2]=t2; kp3[nn][3]=t3; }
#define CONS4(nn,t0,t1,t2,t3) { kp4[nn][0]=t0; kp4[nn][1]=t1; kp4[nn][2]=t2; kp4[nn][3]=t3; }
#define CONS5(nn,t0,t1,t2,t3) { kp5[nn][0]=t0; kp5[nn][1]=t1; kp5[nn][2]=t2; kp5[nn][3]=t3; }
#define CONS6(nn,t0,t1,t2,t3) {                                             \
    y[nn][0] += d1 * kp1[nn][0] + d3 * kp3[nn][0] + d4 * kp4[nn][0]         \
              + d5 * kp5[nn][0] + d6 * (t0);                                \
    y[nn][1] += d1 * kp1[nn][1] + d3 * kp3[nn][1] + d4 * kp4[nn][1]         \
              + d5 * kp5[nn][1] + d6 * (t1);                                \
    y[nn][2] += d1 * kp1[nn][2] + d3 * kp3[nn][2] + d4 * kp4[nn][2]         \
              + d5 * kp5[nn][2] + d6 * (t2);                                \
    y[nn][3] += d1 * kp1[nn][3] + d3 * kp3[nn][3] + d4 * kp4[nn][3]         \
              + d5 * kp5[nn][3] + d6 * (t3); }

__global__ __launch_bounds__(256) void ode_mfma_kernel(const float* __restrict__ y0,
        float* __restrict__ out, const float* __restrict__ W,
        const float* __restrict__ bb, const float* __restrict__ tt, int nrows) {
    __shared__ __align__(16) char smem[32768];
    int tid  = threadIdx.x;
    int lane = tid & 63, w = tid >> 6;
    int l15 = lane & 15, q = lane >> 4;
    int swz = (lane & 7) << 4, q16 = q * 16, q8 = q * 8;
    int rowoff = l15 * 256;
    int g0off = w * 64 + q8, g1off = w * 64 + 32 + q8;

    for (int i = tid; i < 16384; i += 256) {
        int d = i >> 7, c = i & 127;
        unsigned short hb = (unsigned short)bf16r(W[i]);
        *(unsigned short*)(smem + c * 256 + ((d * 2) ^ ((c & 7) << 4))) = hb;
    }
    __syncthreads();

    const char* ab0 = smem + ((2 * w) * 16 + l15) * 256;
    const char* ab1 = smem + ((2 * w + 1) * 16 + l15) * 256;
    short8v af00 = *(const short8v*)(ab0 + ((  0 + q16) ^ swz));
    short8v af01 = *(const short8v*)(ab0 + (( 64 + q16) ^ swz));
    short8v af02 = *(const short8v*)(ab0 + ((128 + q16) ^ swz));
    short8v af03 = *(const short8v*)(ab0 + ((192 + q16) ^ swz));
    short8v af10 = *(const short8v*)(ab1 + ((  0 + q16) ^ swz));
    short8v af11 = *(const short8v*)(ab1 + (( 64 + q16) ^ swz));
    short8v af12 = *(const short8v*)(ab1 + ((128 + q16) ^ swz));
    short8v af13 = *(const short8v*)(ab1 + ((192 + q16) ^ swz));
    __syncthreads();

    float hstep = (tt[1] - tt[0]) * 0.03125f;
    float c21 = hstep * 0.2f;
    float c31 = hstep * 0.075f,               c32 = hstep * 0.225f;
    float c41 = hstep * 0.9777777777777777f,  c42 = hstep * -3.7333333333333334f,
          c43 = hstep * 3.5555555555555554f;
    float c51 = hstep * 2.9525986892242035f,  c52 = hstep * -11.595793324188385f,
          c53 = hstep * 9.822892851699436f,   c54 = hstep * -0.2908093278463649f;
    float c61 = hstep * 2.8462752525252526f,  c62 = hstep * -10.757575757575758f,
          c63 = hstep * 8.906422717743473f,   c64 = hstep * 0.2784090909090909f,
          c65 = hstep * -0.2735313036020583f;
    float d1 = hstep * 0.09114583333333333f,  d3 = hstep * 0.44923629829290207f,
          d4 = hstep * 0.6510416666666666f,   d5 = hstep * -0.322376179245283f,
          d6 = hstep * 0.13095238095238096f;

    f32x4 bias0 = *(const f32x4*)&bb[(2 * w)     * 16 + q * 4];
    f32x4 bias1 = *(const f32x4*)&bb[(2 * w + 1) * 16 + q * 4];

    long grow = (long)blockIdx.x * 16 + l15;
    bool ok = grow < nrows;

    f32x4 y[2];
    if (ok) {
        y[0] = *(const f32x4*)&y0[grow * 128 + (2 * w)     * 16 + q * 4];
        y[1] = *(const f32x4*)&y0[grow * 128 + (2 * w + 1) * 16 + q * 4];
    } else {
        y[0] = (f32x4){0.0f, 0.0f, 0.0f, 0.0f};
        y[1] = (f32x4){0.0f, 0.0f, 0.0f, 0.0f};
    }

    char* bufA = smem;
    char* bufB = smem + 4096;

    f32x4 kp1[2], kp2[2], kp3[2], kp4[2], kp5[2];

    #pragma unroll 1
    for (int step = 0; step < 32; ++step) {
        ODE_STAGE(bufA, YI1, CONS1);
        ODE_STAGE(bufB, YI2, CONS2);
        ODE_STAGE(bufA, YI3, CONS3);
        ODE_STAGE(bufB, YI4, CONS4);
        ODE_STAGE(bufA, YI5, CONS5);
        ODE_STAGE(bufB, YI6, CONS6);
    }

    if (ok) {
        *(f32x4*)&out[grow * 128 + (2 * w)     * 16 + q * 4] = y[0];
        *(f32x4*)&out[grow * 128 + (2 * w + 1) * 16 + q * 4] = y[1];
    }
}

// ---------------------------------------------------------------------------

extern "C" void kernel_launch(void* const* d_in, const int* in_sizes, int n_in,
                              void* d_out, int out_size, void* d_ws, size_t ws_size,
                              hipStream_t stream) {
    const float* x     = (const float*)d_in[0];
    const int*   pei   = (const int*)d_in[1];
    const int*   nei   = (const int*)d_in[2];
    const float* t     = (const float*)d_in[3];
    const float* W_enc = (const float*)d_in[4];
    const float* b_enc = (const float*)d_in[5];
    const float* W_pos = (const float*)d_in[6];
    const float* b_pos = (const float*)d_in[7];
    const float* W_neg = (const float*)d_in[8];
    const float* b_neg = (const float*)d_in[9];
    const float* W_ode = (const float*)d_in[10];
    const float* b_ode = (const float*)d_in[11];

    int n  = in_sizes[0] / 128;   // 50000 nodes
    int nE = in_sizes[1] / 2;     // 800000 edges

    // ws layout (floats): h[n*64] | y0[n*128] | dinvp[n] | dinvn[n]
    // After hw_kernel consumes h, its 12.8MB region is reused for CSR
    // (1.8M ints = 7.2MB): srcp[nE] srcn[nE] cntp[n] cntn[n] rpp[n+1] rpn[n+1]
    float* ws    = (float*)d_ws;
    float* h     = ws;
    float* y0    = ws + (long)n * 64;
    float* dinvp = y0 + (long)n * 128;
    float* dinvn = dinvp + n;

    int* csr  = (int*)h;
    int* srcp = csr;
    int* srcn = srcp + nE;
    int* cntp = srcn + nE;
    int* cntn = cntp + n;
    int* rpp  = cntn + n;
    int* rpn  = rpp + (n + 1);

    // d_out doubles as scratch for hw (pos half then neg half), overwritten by ODE
    float* hwp = (float*)d_out;
    float* hwn = hwp + (long)n * 64;

    const int* psrc = pei;       const int* pdst = pei + nE;
    const int* nsrc = nei;       const int* ndst = nei + nE;

    int nbN = (n + 255) / 256;
    int nbE = (nE + 255) / 256;
    int nbR = (n + 3) / 4;

    encoder_kernel  <<<nbR, 256, 0, stream>>>(x, W_enc, b_enc, h, n);
    hw_kernel       <<<nbR, 256, 0, stream>>>(h, W_pos, W_neg, hwp, hwn, n);
    cnt_zero_kernel <<<nbN, 256, 0, stream>>>(cntp, cntn, n);
    count_kernel    <<<nbE, 256, 0, stream>>>(pdst, ndst, cntp, cntn, nE);
    scan_kernel     <<<2, 1024, 0, stream>>>(cntp, cntn, rpp, rpn, dinvp, dinvn, n);
    fill_kernel     <<<nbE, 256, 0, stream>>>(psrc, pdst, rpp, cntp, srcp, nE);
    fill_kernel     <<<nbE, 256, 0, stream>>>(nsrc, ndst, rpn, cntn, srcn, nE);
    aggregate_kernel<<<nbR, 256, 0, stream>>>(hwp, hwn, srcp, srcn, rpp, rpn,
                                              dinvp, dinvn, b_pos, b_neg, y0, n);
    ode_mfma_kernel <<<(n + 15) / 16, 256, 0, stream>>>(y0, (float*)d_out, W_ode, b_ode, t, n);
}

// Round 20
// 1043.490 us; speedup vs baseline: 1.5955x; 1.0294x over previous
//
#include <hip/hip_runtime.h>
#include <hip/hip_bf16.h>

// ---------------------------------------------------------------------------
// DynamiSE: enc+hw fused GEMM -> CSR build -> fused (gather + dopri5) ODE.
// Round 20: fix r19's aliasing RACE. r19 kept hw in d_out while the fused
// ODE kernel gathers neighbor hw rows AND writes output rows to d_out ->
// early blocks overwrite rows later blocks still need (absmax 0.709).
// Fix: hw lives in ws (hw 25.6MB + CSR 7.2MB + dinv 0.4MB = 33.2MB, fits
// the >=38.8MB ws proven by rounds 4-15). d_out written only by the ODE
// epilogue. Everything else identical to r19.
// ---------------------------------------------------------------------------

typedef __attribute__((ext_vector_type(8))) short short8v;   // 8 bf16 = 4 VGPR
typedef __attribute__((ext_vector_type(4))) float f32x4;
typedef __attribute__((ext_vector_type(2))) unsigned uint2v;

__device__ __forceinline__ float fast_tanh(float x) {
    float e = __builtin_amdgcn_exp2f(x * 2.8853900817779268f);
    return 1.0f - 2.0f * __builtin_amdgcn_rcpf(e + 1.0f);
}

__device__ __forceinline__ unsigned bf16r(float x) {   // RTNE f32->bf16 bits
    unsigned u = __float_as_uint(x);
    return (u + 0x7fffu + ((u >> 16) & 1u)) >> 16;
}
__device__ __forceinline__ unsigned cvt_pk(float lo, float hi) {  // 1 VALU op
    unsigned r;
    asm("v_cvt_pk_bf16_f32 %0, %1, %2" : "=v"(r) : "v"(lo), "v"(hi));
    return r;
}

// ---------------- fused encoder+hw: hw{p,n} = (x@We + be) @ W{p,n} ----------

__global__ __launch_bounds__(256) void enc_hw_kernel(const float* __restrict__ x,
        const float* __restrict__ We, const float* __restrict__ be,
        const float* __restrict__ Wp, const float* __restrict__ Wn,
        float* __restrict__ hwp, float* __restrict__ hwn, int n) {
    __shared__ __align__(16) float Ws[128 * 64];   // 32KB
    __shared__ __align__(16) float Wps[64 * 64];   // 16KB
    __shared__ __align__(16) float Wns[64 * 64];   // 16KB
    __shared__ __align__(16) float xs[4 * 128];    // 2KB
    __shared__ __align__(16) float hs[4 * 64];     // 1KB
    int tid = threadIdx.x;
    for (int i = tid; i < 128 * 64; i += 256) Ws[i] = We[i];
    for (int i = tid; i < 64 * 64; i += 256) { Wps[i] = Wp[i]; Wns[i] = Wn[i]; }
    long row = (long)blockIdx.x * 4;
    for (int i = tid; i < 4 * 128; i += 256) {
        long rr = row + (i >> 7);
        xs[i] = (rr < n) ? x[rr * 128 + (i & 127)] : 0.0f;
    }
    __syncthreads();
    int r = tid >> 6, c = tid & 63;
    float acc = be[c];
    #pragma unroll 8
    for (int k = 0; k < 128; k += 4) {
        float4 xv = *(const float4*)&xs[r * 128 + k];
        acc += xv.x * Ws[(k+0)*64+c] + xv.y * Ws[(k+1)*64+c]
             + xv.z * Ws[(k+2)*64+c] + xv.w * Ws[(k+3)*64+c];
    }
    hs[r * 64 + c] = acc;
    __syncthreads();
    float ap = 0.0f, an = 0.0f;
    #pragma unroll 4
    for (int k = 0; k < 64; k += 4) {
        float4 hv = *(const float4*)&hs[r * 64 + k];
        ap += hv.x*Wps[(k+0)*64+c] + hv.y*Wps[(k+1)*64+c] + hv.z*Wps[(k+2)*64+c] + hv.w*Wps[(k+3)*64+c];
        an += hv.x*Wns[(k+0)*64+c] + hv.y*Wns[(k+1)*64+c] + hv.z*Wns[(k+2)*64+c] + hv.w*Wns[(k+3)*64+c];
    }
    if (row + r < n) {
        hwp[(row + r) * 64 + c] = ap;
        hwn[(row + r) * 64 + c] = an;
    }
}

// ---------------- CSR build: count / scan / fill ----------------

__global__ __launch_bounds__(256) void count_kernel(const int* __restrict__ pdst,
        const int* __restrict__ ndst, int* cntp, int* cntn, int nE) {
    int e = blockIdx.x * 256 + threadIdx.x;
    if (e < nE) {
        atomicAdd(&cntp[pdst[e]], 1);
        atomicAdd(&cntn[ndst[e]], 1);
    }
}

// grid = 2 blocks (0: pos, 1: neg), 1024 threads. Exclusive scan cnt->rowptr,
// dinv = rsqrt(cnt+1) (self-loop), cnt zeroed for reuse as fill cursor.
__global__ __launch_bounds__(1024) void scan_kernel(int* cntp, int* cntn,
        int* rpp, int* rpn, float* dinvp, float* dinvn, int n) {
    int* cnt  = blockIdx.x ? cntn  : cntp;
    int* rp   = blockIdx.x ? rpn   : rpp;
    float* dv = blockIdx.x ? dinvn : dinvp;
    __shared__ int ps[1024];
    int t = threadIdx.x;
    int CH = (n + 1023) / 1024;
    int beg = t * CH, end = beg + CH; if (end > n) end = n;
    int s = 0;
    for (int i = beg; i < end && i >= 0; ++i) s += cnt[i];
    ps[t] = s;
    __syncthreads();
    for (int off = 1; off < 1024; off <<= 1) {
        int v = (t >= off) ? ps[t - off] : 0;
        __syncthreads();
        ps[t] += v;
        __syncthreads();
    }
    int run = (t == 0) ? 0 : ps[t - 1];
    for (int i = beg; i < end && i >= 0; ++i) {
        int c = cnt[i];
        rp[i] = run; run += c;
        dv[i] = rsqrtf((float)c + 1.0f);
        cnt[i] = 0;
    }
    if (t == 1023) rp[n] = ps[1023];
}

__global__ __launch_bounds__(256) void fill_kernel(const int* __restrict__ src,
        const int* __restrict__ dst, const int* __restrict__ rp,
        int* cur, int* outarr, int nE) {
    int e = blockIdx.x * 256 + threadIdx.x;
    if (e >= nE) return;
    int d = dst[e];
    int pos = rp[d] + atomicAdd(&cur[d], 1);
    outarr[pos] = src[e];
}

// ---------------- fused gather + dopri5 ODE, bf16 MFMA --------------------
// Block: 256 threads = 4 waves, ONE 16-node group. Wave w owns col-groups
// {2w, 2w+1} of the 128-wide state; w<2 -> pos-graph cols [0,64),
// w>=2 -> neg-graph cols [64,128). Prologue gathers y0 for this block's 16
// nodes directly from CSR+hw (in ws - NOT aliased with out) into per-thread
// y registers. Main loop identical to r15/r18.

#define MFMA_(A, B, C) __builtin_amdgcn_mfma_f32_16x16x32_bf16(A, B, C, 0, 0, 0)

#define ODE_STAGE(BUF, YIM, CONSM) {                                                \
    char* yr_ = (BUF) + rowoff;                                                     \
    uint2v pk_;                                                                     \
    pk_.x = cvt_pk(YIM(0,0), YIM(0,1)); pk_.y = cvt_pk(YIM(0,2), YIM(0,3));         \
    *(uint2v*)(yr_ + (g0off ^ swz)) = pk_;                                          \
    pk_.x = cvt_pk(YIM(1,0), YIM(1,1)); pk_.y = cvt_pk(YIM(1,2), YIM(1,3));         \
    *(uint2v*)(yr_ + (g1off ^ swz)) = pk_;                                          \
    __syncthreads();                                                                \
    short8v b0 = *(const short8v*)(yr_ + ((  0 + q16) ^ swz));                      \
    short8v b1 = *(const short8v*)(yr_ + (( 64 + q16) ^ swz));                      \
    short8v b2 = *(const short8v*)(yr_ + ((128 + q16) ^ swz));                      \
    short8v b3 = *(const short8v*)(yr_ + ((192 + q16) ^ swz));                      \
    {                                                                               \
        f32x4 a = bias0;                                                            \
        a = MFMA_(af00, b0, a); a = MFMA_(af01, b1, a);                             \
        a = MFMA_(af02, b2, a); a = MFMA_(af03, b3, a);                             \
        CONSM(0, fast_tanh(a[0]), fast_tanh(a[1]), fast_tanh(a[2]), fast_tanh(a[3])); \
    }                                                                               \
    {                                                                               \
        f32x4 a = bias1;                                                            \
        a = MFMA_(af10, b0, a); a = MFMA_(af11, b1, a);                             \
        a = MFMA_(af12, b2, a); a = MFMA_(af13, b3, a);                             \
        CONSM(1, fast_tanh(a[0]), fast_tanh(a[1]), fast_tanh(a[2]), fast_tanh(a[3])); \
    } }

#define YI1(nn, r) (y[nn][r])
#define YI2(nn, r) (y[nn][r] + c21 * kp1[nn][r])
#define YI3(nn, r) (y[nn][r] + c31 * kp1[nn][r] + c32 * kp2[nn][r])
#define YI4(nn, r) (y[nn][r] + c41 * kp1[nn][r] + c42 * kp2[nn][r] + c43 * kp3[nn][r])
#define YI5(nn, r) (y[nn][r] + c51 * kp1[nn][r] + c52 * kp2[nn][r] + c53 * kp3[nn][r] \
                             + c54 * kp4[nn][r])
#define YI6(nn, r) (y[nn][r] + c61 * kp1[nn][r] + c62 * kp2[nn][r] + c63 * kp3[nn][r] \
                             + c64 * kp4[nn][r] + c65 * kp5[nn][r])

#define CONS1(nn,t0,t1,t2,t3) { kp1[nn][0]=t0; kp1[nn][1]=t1; kp1[nn][2]=t2; kp1[nn][3]=t3; }
#define CONS2(nn,t0,t1,t2,t3) { kp2[nn][0]=t0; kp2[nn][1]=t1; kp2[nn][2]=t2; kp2[nn][3]=t3; }
#define CONS3(nn,t0,t1,t2,t3) { kp3[nn][0]=t0; kp3[nn][1]=t1; kp3[nn][2]=t2; kp3[nn][3]=t3; }
#define CONS4(nn,t0,t1,t2,t3) { kp4[nn][0]=t0; kp4[nn][1]=t1; kp4[nn][2]=t2; kp4[nn][3]=t3; }
#define CONS5(nn,t0,t1,t2,t3) { kp5[nn][0]=t0; kp5[nn][1]=t1; kp5[nn][2]=t2; kp5[nn][3]=t3; }
#define CONS6(nn,t0,t1,t2,t3) {                                             \
    y[nn][0] += d1 * kp1[nn][0] + d3 * kp3[nn][0] + d4 * kp4[nn][0]         \
              + d5 * kp5[nn][0] + d6 * (t0);                                \
    y[nn][1] += d1 * kp1[nn][1] + d3 * kp3[nn][1] + d4 * kp4[nn][1]         \
              + d5 * kp5[nn][1] + d6 * (t1);                                \
    y[nn][2] += d1 * kp1[nn][2] + d3 * kp3[nn][2] + d4 * kp4[nn][2]         \
              + d5 * kp5[nn][2] + d6 * (t2);                                \
    y[nn][3] += d1 * kp1[nn][3] + d3 * kp3[nn][3] + d4 * kp4[nn][3]         \
              + d5 * kp5[nn][3] + d6 * (t3); }

__global__ __launch_bounds__(256) void ode_mfma_kernel(
        const float* __restrict__ hwp, const float* __restrict__ hwn,
        const int* __restrict__ srcp, const int* __restrict__ srcn,
        const int* __restrict__ rpp, const int* __restrict__ rpn,
        const float* __restrict__ dinvp, const float* __restrict__ dinvn,
        const float* __restrict__ gbp, const float* __restrict__ gbn,
        float* __restrict__ out, const float* __restrict__ W,
        const float* __restrict__ bb, const float* __restrict__ tt, int nrows) {
    __shared__ __align__(16) char smem[32768];
    int tid  = threadIdx.x;
    int lane = tid & 63, w = tid >> 6;       // w: col-group pair {2w, 2w+1}
    int l15 = lane & 15, q = lane >> 4;
    int swz = (lane & 7) << 4, q16 = q * 16, q8 = q * 8;
    int rowoff = l15 * 256;
    int g0off = w * 64 + q8, g1off = w * 64 + 32 + q8;

    // stage W^T (bf16, swizzled): Wt[c][d] = W[d][c]
    for (int i = tid; i < 16384; i += 256) {
        int d = i >> 7, c = i & 127;
        unsigned short hb = (unsigned short)bf16r(W[i]);
        *(unsigned short*)(smem + c * 256 + ((d * 2) ^ ((c & 7) << 4))) = hb;
    }
    __syncthreads();

    // cache my 8 A-fragments (2 col-groups x 4 k-slices) in registers
    const char* ab0 = smem + ((2 * w) * 16 + l15) * 256;
    const char* ab1 = smem + ((2 * w + 1) * 16 + l15) * 256;
    short8v af00 = *(const short8v*)(ab0 + ((  0 + q16) ^ swz));
    short8v af01 = *(const short8v*)(ab0 + (( 64 + q16) ^ swz));
    short8v af02 = *(const short8v*)(ab0 + ((128 + q16) ^ swz));
    short8v af03 = *(const short8v*)(ab0 + ((192 + q16) ^ swz));
    short8v af10 = *(const short8v*)(ab1 + ((  0 + q16) ^ swz));
    short8v af11 = *(const short8v*)(ab1 + (( 64 + q16) ^ swz));
    short8v af12 = *(const short8v*)(ab1 + ((128 + q16) ^ swz));
    short8v af13 = *(const short8v*)(ab1 + ((192 + q16) ^ swz));
    __syncthreads();   // all A-frags cached -> first 8KB may be clobbered

    float hstep = (tt[1] - tt[0]) * 0.03125f;
    float c21 = hstep * 0.2f;
    float c31 = hstep * 0.075f,               c32 = hstep * 0.225f;
    float c41 = hstep * 0.9777777777777777f,  c42 = hstep * -3.7333333333333334f,
          c43 = hstep * 3.5555555555555554f;
    float c51 = hstep * 2.9525986892242035f,  c52 = hstep * -11.595793324188385f,
          c53 = hstep * 9.822892851699436f,   c54 = hstep * -0.2908093278463649f;
    float c61 = hstep * 2.8462752525252526f,  c62 = hstep * -10.757575757575758f,
          c63 = hstep * 8.906422717743473f,   c64 = hstep * 0.2784090909090909f,
          c65 = hstep * -0.2735313036020583f;
    float d1 = hstep * 0.09114583333333333f,  d3 = hstep * 0.44923629829290207f,
          d4 = hstep * 0.6510416666666666f,   d5 = hstep * -0.322376179245283f,
          d6 = hstep * 0.13095238095238096f;

    // ODE bias (b_ode) for my 2 col-groups
    f32x4 bias0 = *(const f32x4*)&bb[(2 * w)     * 16 + q * 4];
    f32x4 bias1 = *(const f32x4*)&bb[(2 * w + 1) * 16 + q * 4];

    long grow = (long)blockIdx.x * 16 + l15;
    bool ok = grow < nrows;

    // ---- gather prologue: y0 for node `grow`, my 8 cols ----
    // w<2 -> pos graph (state cols 0-63); w>=2 -> neg graph (cols 64-127)
    const float* hwA  = (w < 2) ? hwp   : hwn;
    const int*   srcA = (w < 2) ? srcp  : srcn;
    const int*   rpA  = (w < 2) ? rpp   : rpn;
    const float* dvA  = (w < 2) ? dinvp : dinvn;
    const float* gbA  = (w < 2) ? gbp   : gbn;
    int col0 = ((2 * w) & 3) * 16 + q * 4;   // hw-row col of group 2w
    int col1 = col0 + 16;                    // hw-row col of group 2w+1

    f32x4 y[2];
    y[0] = (f32x4){0.0f, 0.0f, 0.0f, 0.0f};
    y[1] = (f32x4){0.0f, 0.0f, 0.0f, 0.0f};
    if (ok) {
        int dnode = (int)grow;
        int beg = rpA[dnode], end = rpA[dnode + 1];
        for (int i = beg; i < end; ++i) {
            int a = srcA[i];
            float dva = dvA[a];
            f32x4 h0 = *(const f32x4*)&hwA[(long)a * 64 + col0];
            f32x4 h1 = *(const f32x4*)&hwA[(long)a * 64 + col1];
            #pragma unroll
            for (int r = 0; r < 4; ++r) { y[0][r] += dva * h0[r]; y[1][r] += dva * h1[r]; }
        }
        float dvd = dvA[dnode];
        f32x4 h0 = *(const f32x4*)&hwA[(long)dnode * 64 + col0];
        f32x4 h1 = *(const f32x4*)&hwA[(long)dnode * 64 + col1];
        f32x4 gb0 = *(const f32x4*)&gbA[col0];
        f32x4 gb1 = *(const f32x4*)&gbA[col1];
        #pragma unroll
        for (int r = 0; r < 4; ++r) {
            y[0][r] = dvd * (y[0][r] + dvd * h0[r]) + gb0[r];
            y[1][r] = dvd * (y[1][r] + dvd * h1[r]) + gb1[r];
        }
    }

    char* bufA = smem;
    char* bufB = smem + 4096;

    f32x4 kp1[2], kp2[2], kp3[2], kp4[2], kp5[2];

    #pragma unroll 1
    for (int step = 0; step < 32; ++step) {
        ODE_STAGE(bufA, YI1, CONS1);
        ODE_STAGE(bufB, YI2, CONS2);
        ODE_STAGE(bufA, YI3, CONS3);
        ODE_STAGE(bufB, YI4, CONS4);
        ODE_STAGE(bufA, YI5, CONS5);
        ODE_STAGE(bufB, YI6, CONS6);
    }

    if (ok) {
        *(f32x4*)&out[grow * 128 + (2 * w)     * 16 + q * 4] = y[0];
        *(f32x4*)&out[grow * 128 + (2 * w + 1) * 16 + q * 4] = y[1];
    }
}

// ---------------------------------------------------------------------------

extern "C" void kernel_launch(void* const* d_in, const int* in_sizes, int n_in,
                              void* d_out, int out_size, void* d_ws, size_t ws_size,
                              hipStream_t stream) {
    const float* x     = (const float*)d_in[0];
    const int*   pei   = (const int*)d_in[1];
    const int*   nei   = (const int*)d_in[2];
    const float* t     = (const float*)d_in[3];
    const float* W_enc = (const float*)d_in[4];
    const float* b_enc = (const float*)d_in[5];
    const float* W_pos = (const float*)d_in[6];
    const float* b_pos = (const float*)d_in[7];
    const float* W_neg = (const float*)d_in[8];
    const float* b_neg = (const float*)d_in[9];
    const float* W_ode = (const float*)d_in[10];
    const float* b_ode = (const float*)d_in[11];

    int n  = in_sizes[0] / 128;   // 50000 nodes
    int nE = in_sizes[1] / 2;     // 800000 edges

    // ws layout (NO aliasing with d_out):
    //   floats hwp[n*64], hwn[n*64]  (25.6MB)
    //   ints   srcp[nE], srcn[nE], cntp[n], cntn[n], rpp[n+1], rpn[n+1] (7.2MB)
    //   floats dinvp[n], dinvn[n]    (0.4MB)           total ~33.2MB
    float* hwp = (float*)d_ws;
    float* hwn = hwp + (long)n * 64;
    int* srcp = (int*)(hwn + (long)n * 64);
    int* srcn = srcp + nE;
    int* cntp = srcn + nE;
    int* cntn = cntp + n;            // cntp,cntn contiguous -> single memset
    int* rpp  = cntn + n;
    int* rpn  = rpp + (n + 1);
    float* dinvp = (float*)(rpn + (n + 1));
    float* dinvn = dinvp + n;

    const int* psrc = pei;       const int* pdst = pei + nE;
    const int* nsrc = nei;       const int* ndst = nei + nE;

    int nbE = (nE + 255) / 256;
    int nbR = (n + 3) / 4;

    enc_hw_kernel   <<<nbR, 256, 0, stream>>>(x, W_enc, b_enc, W_pos, W_neg, hwp, hwn, n);
    hipMemsetAsync(cntp, 0, (size_t)(2 * n) * sizeof(int), stream);
    count_kernel    <<<nbE, 256, 0, stream>>>(pdst, ndst, cntp, cntn, nE);
    scan_kernel     <<<2, 1024, 0, stream>>>(cntp, cntn, rpp, rpn, dinvp, dinvn, n);
    fill_kernel     <<<nbE, 256, 0, stream>>>(psrc, pdst, rpp, cntp, srcp, nE);
    fill_kernel     <<<nbE, 256, 0, stream>>>(nsrc, ndst, rpn, cntn, srcn, nE);
    ode_mfma_kernel <<<(n + 15) / 16, 256, 0, stream>>>(hwp, hwn, srcp, srcn, rpp, rpn,
                                                        dinvp, dinvn, b_pos, b_neg,
                                                        (float*)d_out, W_ode, b_ode, t, n);
}